// Round 1
// baseline (177.354 us; speedup 1.0000x reference)
//
#include <hip/hip_runtime.h>

// Problem constants
#define TDIM 2048
#define CDIM 256

typedef __bf16 bf16_t;
typedef bf16_t bf16x8 __attribute__((ext_vector_type(8)));
typedef float f32x4 __attribute__((ext_vector_type(4)));

__device__ __forceinline__ unsigned short f2bf(float x) {
  unsigned u = __builtin_bit_cast(unsigned, x);
  u += 0x7fffu + ((u >> 16) & 1u);            // round-to-nearest-even
  return (unsigned short)(u >> 16);
}

// ---------------------------------------------------------------------------
// K1: fused 1x1 conv + BN + ReLU for K/Q/V  ->  qkv[b][384][T] bf16
//     channels 0..63 = key, 64..127 = query, 128..383 = value
// grid (32 t-tiles, 3 oc-groups of 128, 8 batches), block 256
// ---------------------------------------------------------------------------
__global__ __launch_bounds__(256) void k_qkv(
    const float* __restrict__ x,
    const float* __restrict__ kW, const float* __restrict__ kb,
    const float* __restrict__ kg, const float* __restrict__ kbe,
    const float* __restrict__ kmu, const float* __restrict__ kva,
    const float* __restrict__ qW, const float* __restrict__ qb,
    const float* __restrict__ qg, const float* __restrict__ qbe,
    const float* __restrict__ qmu, const float* __restrict__ qva,
    const float* __restrict__ vW, const float* __restrict__ vb,
    const float* __restrict__ vg, const float* __restrict__ vbe,
    const float* __restrict__ vmu, const float* __restrict__ vva,
    unsigned short* __restrict__ qkv)
{
  const int tb  = blockIdx.x;
  const int gid = blockIdx.y;
  const int b   = blockIdx.z;
  const int tid = threadIdx.x;
  const int lane = tid & 63, wv = tid >> 6;
  const int m = lane & 15, quad = lane >> 4;
  const int t0 = tb * 64;

  __shared__ unsigned short Ws[128 * 136];  // one K-half: 128 oc x 128 c (+8 pad)
  __shared__ unsigned short Xs[64 * 72];    // 64 t x 64 c, XOR-swizzled
  __shared__ float invs[128];
  __shared__ float effbs[128];

  if (tid < 128) {
    int G = gid * 128 + tid;
    float gg = (G < 64) ? kg[G]  : (G < 128) ? qg[G - 64]  : vg[G - 128];
    float vvv= (G < 64) ? kva[G] : (G < 128) ? qva[G - 64] : vva[G - 128];
    float bb = (G < 64) ? kb[G]  : (G < 128) ? qb[G - 64]  : vb[G - 128];
    float mm = (G < 64) ? kmu[G] : (G < 128) ? qmu[G - 64] : vmu[G - 128];
    float be = (G < 64) ? kbe[G] : (G < 128) ? qbe[G - 64] : vbe[G - 128];
    float inv = gg * rsqrtf(vvv + 1e-5f);
    invs[tid]  = inv;
    effbs[tid] = (bb - mm) * inv + be;
  }
  __syncthreads();

  const f32x4 fz = {0.f, 0.f, 0.f, 0.f};
  f32x4 acc[2][4];
#pragma unroll
  for (int i = 0; i < 2; ++i)
#pragma unroll
    for (int j = 0; j < 4; ++j) acc[i][j] = fz;

  for (int ch = 0; ch < 2; ++ch) {
    __syncthreads();  // protect Ws from previous half's reads
    // stage effW half (BN-folded, bf16): rows 0..127, cols [ch*128, ch*128+128)
#pragma unroll 4
    for (int it = 0; it < 16; ++it) {
      int idx = it * 256 + tid;      // 0..4095 float4s
      int row = idx >> 5;            // 32 float4 per row
      int c4  = (idx & 31) * 4;
      int G = gid * 128 + row;
      const float* Wp = (G < 64) ? (kW + G * 256)
                       : (G < 128) ? (qW + (G - 64) * 256)
                                   : (vW + (G - 128) * 256);
      float4 w4 = *(const float4*)(Wp + ch * 128 + c4);
      float inv = invs[row];
      ushort4 s4;
      s4.x = f2bf(w4.x * inv); s4.y = f2bf(w4.y * inv);
      s4.z = f2bf(w4.z * inv); s4.w = f2bf(w4.w * inv);
      *(ushort4*)&Ws[row * 136 + c4] = s4;
    }
    for (int cx = 0; cx < 2; ++cx) {
      __syncthreads();  // Ws ready / protect Xs
      {
        int t  = tid & 63;
        int cb = b * 256 + ch * 128 + cx * 64;
#pragma unroll 4
        for (int i = 0; i < 16; ++i) {
          int c = i * 4 + (tid >> 6);
          float v = x[(size_t)(cb + c) * TDIM + t0 + t];
          int csw = (((c >> 3) ^ (t >> 3)) << 3) | (c & 7);
          Xs[t * 72 + csw] = f2bf(v);
        }
      }
      __syncthreads();
#pragma unroll
      for (int kk = 0; kk < 2; ++kk) {
        bf16x8 af[2];
#pragma unroll
        for (int mt = 0; mt < 2; ++mt) {
          int row = wv * 32 + mt * 16 + m;
          af[mt] = *(const bf16x8*)&Ws[row * 136 + cx * 64 + kk * 32 + quad * 8];
        }
#pragma unroll
        for (int nt = 0; nt < 4; ++nt) {
          int t = nt * 16 + m;
          int blk = (kk * 4 + quad) ^ (t >> 3);
          bf16x8 bfr = *(const bf16x8*)&Xs[t * 72 + blk * 8];
          acc[0][nt] = __builtin_amdgcn_mfma_f32_16x16x32_bf16(af[0], bfr, acc[0][nt], 0, 0, 0);
          acc[1][nt] = __builtin_amdgcn_mfma_f32_16x16x32_bf16(af[1], bfr, acc[1][nt], 0, 0, 0);
        }
      }
    }
  }
  // epilogue: +effb, ReLU, bf16 store.  D layout: row=quad*4+r (oc), col=m (t)
#pragma unroll
  for (int mt = 0; mt < 2; ++mt)
#pragma unroll
    for (int nt = 0; nt < 4; ++nt)
#pragma unroll
      for (int r = 0; r < 4; ++r) {
        int ocl = wv * 32 + mt * 16 + quad * 4 + r;
        float y = acc[mt][nt][r] + effbs[ocl];
        y = fmaxf(y, 0.f);
        int oc = gid * 128 + ocl;
        int t  = t0 + nt * 16 + m;
        qkv[(size_t)(b * 384 + oc) * TDIM + t] = f2bf(y);
      }
}

// ---------------------------------------------------------------------------
// Shared helpers for attention kernels
// ---------------------------------------------------------------------------
__device__ __forceinline__ void stage_qk(const unsigned short* __restrict__ qkv,
                                         int b, int t0, int tid,
                                         unsigned short* Qs, unsigned short* Ks)
{
  const unsigned short* Qg = qkv + (size_t)(b * 384 + 64) * TDIM;
  const unsigned short* Kg = qkv + (size_t)(b * 384) * TDIM;
  int t2  = (tid & 31) * 2;
  int dd0 = tid >> 5;
#pragma unroll 2
  for (int dp = 0; dp < 8; ++dp) {
    int dd  = dp * 8 + dd0;
    int blk = dd >> 3, dl = dd & 7;
    ushort2 v = *(const ushort2*)(Qg + (size_t)dd * TDIM + t0 + t2);
    int t_ = t2;
    Qs[t_ * 72 + ((blk ^ (t_ >> 3)) << 3) + dl] = v.x;
    t_ = t2 + 1;
    Qs[t_ * 72 + ((blk ^ (t_ >> 3)) << 3) + dl] = v.y;
#pragma unroll
    for (int sp = 0; sp < 5; ++sp) {
      int s  = sp * 64 + t2;
      int sg = t0 - 256 + s;
      ushort2 kv2; kv2.x = 0; kv2.y = 0;
      if (sg >= 0) kv2 = *(const ushort2*)(Kg + (size_t)dd * TDIM + sg);
      int s_ = s;
      Ks[s_ * 72 + (((blk ^ (s_ >> 3)) & 7) << 3) + dl] = kv2.x;
      s_ = s + 1;
      Ks[s_ * 72 + (((blk ^ (s_ >> 3)) & 7) << 3) + dl] = kv2.y;
    }
  }
}

__device__ __forceinline__ void score17(const unsigned short* Qs, const unsigned short* Ks,
                                        int wv, int m, int quad, f32x4* sc)
{
  bf16x8 qf[2];
  int t = wv * 16 + m;
#pragma unroll
  for (int kk = 0; kk < 2; ++kk)
    qf[kk] = *(const bf16x8*)&Qs[t * 72 + (((kk * 4 + quad) ^ (t >> 3)) << 3)];
  const f32x4 fz = {0.f, 0.f, 0.f, 0.f};
#pragma unroll
  for (int j = 0; j < 17; ++j) {
    f32x4 a = fz;
    int sr = 16 * (wv + j) + m;
    int s3 = (sr >> 3) & 7;
    bf16x8 kf0 = *(const bf16x8*)&Ks[sr * 72 + ((quad ^ s3) << 3)];
    a = __builtin_amdgcn_mfma_f32_16x16x32_bf16(qf[0], kf0, a, 0, 0, 0);
    bf16x8 kf1 = *(const bf16x8*)&Ks[sr * 72 + (((4 + quad) ^ s3) << 3)];
    a = __builtin_amdgcn_mfma_f32_16x16x32_bf16(qf[1], kf1, a, 0, 0, 0);
    sc[j] = a;
  }
}

// ---------------------------------------------------------------------------
// K2a: batch-0 row denominators (the reference's [0]-broadcast bug).  grid 32.
// ---------------------------------------------------------------------------
__global__ __launch_bounds__(256) void k_denom(const unsigned short* __restrict__ qkv,
                                               float* __restrict__ denom0)
{
  const int tb = blockIdx.x;
  const int tid = threadIdx.x;
  const int lane = tid & 63, wv = tid >> 6;
  const int m = lane & 15, quad = lane >> 4;
  const int t0 = tb * 64;
  __shared__ unsigned short Qs[64 * 72];
  __shared__ unsigned short Ks[320 * 72];
  stage_qk(qkv, 0, t0, tid, Qs, Ks);
  __syncthreads();
  f32x4 sc[17];
  score17(Qs, Ks, wv, m, quad, sc);
  const int tw = t0 + wv * 16;
  float mx[4] = {0.f, 0.f, 0.f, 0.f};   // masked entries are 0 before the max
#pragma unroll
  for (int j = 0; j < 17; ++j)
#pragma unroll
    for (int r = 0; r < 4; ++r) {
      float v = sc[j][r] * 0.125f;
      sc[j][r] = v;
      int tg = tw + quad * 4 + r;
      int sg = tw - 256 + 16 * j + m;
      if (sg >= 0 && sg <= tg && tg - sg < 256) mx[r] = fmaxf(mx[r], v);
    }
#pragma unroll
  for (int d = 1; d < 16; d <<= 1)
#pragma unroll
    for (int r = 0; r < 4; ++r) mx[r] = fmaxf(mx[r], __shfl_xor(mx[r], d, 64));
  float sm[4] = {0.f, 0.f, 0.f, 0.f};
#pragma unroll
  for (int j = 0; j < 17; ++j)
#pragma unroll
    for (int r = 0; r < 4; ++r) {
      int tg = tw + quad * 4 + r;
      int sg = tw - 256 + 16 * j + m;
      if (sg >= 0 && sg <= tg && tg - sg < 256) sm[r] += __expf(sc[j][r] - mx[r]);
    }
#pragma unroll
  for (int d = 1; d < 16; d <<= 1)
#pragma unroll
    for (int r = 0; r < 4; ++r) sm[r] += __shfl_xor(sm[r], d, 64);
  if (m == 0)
#pragma unroll
    for (int r = 0; r < 4; ++r) denom0[tw + quad * 4 + r] = sm[r];
}

// ---------------------------------------------------------------------------
// K2b: banded attention + residual.  grid (32 t-tiles, 8 batches), block 256.
// LDS is phase-unioned: {Qs,Ks} -> {Ps,Vs} (62.4 KB static).
// ---------------------------------------------------------------------------
__global__ __launch_bounds__(256) void k_attn(
    const float* __restrict__ x,
    const unsigned short* __restrict__ qkv,
    const float* __restrict__ denom0,
    float* __restrict__ out)
{
  const int tb = blockIdx.x, b = blockIdx.y;
  const int tid = threadIdx.x;
  const int lane = tid & 63, wv = tid >> 6;
  const int m = lane & 15, quad = lane >> 4;
  const int t0 = tb * 64;

  __shared__ unsigned short SM[31232];
  unsigned short* Qs = SM;            // phase 1: 64*72   = 4608
  unsigned short* Ks = SM + 4608;     // phase 1: 320*72  = 23040
  unsigned short* Ps = SM;            // phase 2: 4*16*328= 20992
  unsigned short* Vs = SM + 20992;    // phase 2: 256*40  = 10240

  stage_qk(qkv, b, t0, tid, Qs, Ks);
  __syncthreads();
  f32x4 sc[17];
  score17(Qs, Ks, wv, m, quad, sc);
  const int tw = t0 + wv * 16;
  float mx[4] = {0.f, 0.f, 0.f, 0.f};
#pragma unroll
  for (int j = 0; j < 17; ++j)
#pragma unroll
    for (int r = 0; r < 4; ++r) {
      float v = sc[j][r] * 0.125f;
      sc[j][r] = v;
      int tg = tw + quad * 4 + r;
      int sg = tw - 256 + 16 * j + m;
      if (sg >= 0 && sg <= tg && tg - sg < 256) mx[r] = fmaxf(mx[r], v);
    }
#pragma unroll
  for (int d = 1; d < 16; d <<= 1)
#pragma unroll
    for (int r = 0; r < 4; ++r) mx[r] = fmaxf(mx[r], __shfl_xor(mx[r], d, 64));
  float rden[4];
#pragma unroll
  for (int r = 0; r < 4; ++r)
    rden[r] = 1.f / (denom0[tw + quad * 4 + r] + 1e-30f);
#pragma unroll
  for (int j = 0; j < 17; ++j)
#pragma unroll
    for (int r = 0; r < 4; ++r) {
      int tg = tw + quad * 4 + r;
      int sg = tw - 256 + 16 * j + m;
      bool ib = (sg >= 0 && sg <= tg && tg - sg < 256);
      sc[j][r] = ib ? __expf(sc[j][r] - mx[r]) * rden[r] : 0.f;
    }
  __syncthreads();  // all Qs/Ks reads retired -> safe to overwrite with Ps

  // write P (already normalized) into LDS in A-operand-friendly layout
  unsigned short* Pw = Ps + wv * (16 * 328);
  for (int i = lane; i < 1312; i += 64) {
    ushort4 z; z.x = 0; z.y = 0; z.z = 0; z.w = 0;
    *(ushort4*)(Pw + i * 4) = z;
  }
#pragma unroll
  for (int j = 0; j < 17; ++j)
#pragma unroll
    for (int r = 0; r < 4; ++r)
      Pw[(quad * 4 + r) * 328 + 16 * wv + 16 * j + m] = f2bf(sc[j][r]);

  // PV: wave wv owns c-strip [64*wv, 64*wv+64); V staged in 32-s chunks
  const f32x4 fz = {0.f, 0.f, 0.f, 0.f};
  f32x4 acc[4][4];
#pragma unroll
  for (int i = 0; i < 4; ++i)
#pragma unroll
    for (int j = 0; j < 4; ++j) acc[i][j] = fz;
  const unsigned short* Vg = qkv + (size_t)(b * 384 + 128) * TDIM;

  for (int chunk = 0; chunk < 10; ++chunk) {
    __syncthreads();  // Vs reuse + (chunk 0) Ps visibility
    {
      int s4 = (tid & 7) * 4;
      int c0 = tid >> 3;
      int sg = t0 - 256 + chunk * 32 + s4;
#pragma unroll
      for (int p = 0; p < 8; ++p) {
        int c = p * 32 + c0;
        ushort4 v; v.x = 0; v.y = 0; v.z = 0; v.w = 0;
        if (sg >= 0) v = *(const ushort4*)(Vg + (size_t)c * TDIM + sg);
        *(ushort4*)&Vs[c * 40 + s4] = v;
      }
    }
    __syncthreads();
    int kcol = chunk * 32;
    bf16x8 vf[4];
#pragma unroll
    for (int nt = 0; nt < 4; ++nt)
      vf[nt] = *(const bf16x8*)&Vs[(wv * 64 + nt * 16 + m) * 40 + quad * 8];
#pragma unroll
    for (int mt = 0; mt < 4; ++mt) {
      bf16x8 pf = *(const bf16x8*)&Ps[mt * (16 * 328) + m * 328 + kcol + quad * 8];
#pragma unroll
      for (int nt = 0; nt < 4; ++nt)
        acc[mt][nt] = __builtin_amdgcn_mfma_f32_16x16x32_bf16(pf, vf[nt], acc[mt][nt], 0, 0, 0);
    }
  }

  // epilogue: out = x + tsa^T ; lane's 4 regs are 4 consecutive t -> float4
#pragma unroll
  for (int mt = 0; mt < 4; ++mt)
#pragma unroll
    for (int nt = 0; nt < 4; ++nt) {
      int c = wv * 64 + nt * 16 + m;
      int t = t0 + mt * 16 + quad * 4;
      size_t off = (size_t)(b * 256 + c) * TDIM + t;
      float4 xv = *(const float4*)(x + off);
      float4 o;
      o.x = xv.x + acc[mt][nt][0];
      o.y = xv.y + acc[mt][nt][1];
      o.z = xv.z + acc[mt][nt][2];
      o.w = xv.w + acc[mt][nt][3];
      *(float4*)(out + off) = o;
    }
}

// ---------------------------------------------------------------------------
extern "C" void kernel_launch(void* const* d_in, const int* in_sizes, int n_in,
                              void* d_out, int out_size, void* d_ws, size_t ws_size,
                              hipStream_t stream) {
  const float* x   = (const float*)d_in[0];
  const float* kW  = (const float*)d_in[1];
  const float* kb  = (const float*)d_in[2];
  const float* kg  = (const float*)d_in[3];
  const float* kbe = (const float*)d_in[4];
  const float* kmu = (const float*)d_in[5];
  const float* kva = (const float*)d_in[6];
  const float* qW  = (const float*)d_in[7];
  const float* qb  = (const float*)d_in[8];
  const float* qg  = (const float*)d_in[9];
  const float* qbe = (const float*)d_in[10];
  const float* qmu = (const float*)d_in[11];
  const float* qva = (const float*)d_in[12];
  const float* vW  = (const float*)d_in[13];
  const float* vb  = (const float*)d_in[14];
  const float* vg  = (const float*)d_in[15];
  const float* vbe = (const float*)d_in[16];
  const float* vmu = (const float*)d_in[17];
  const float* vva = (const float*)d_in[18];

  unsigned short* qkv = (unsigned short*)d_ws;                       // 8*384*2048 bf16 = 12.58 MB
  float* denom0 = (float*)((char*)d_ws + (size_t)8 * 384 * 2048 * 2); // 2048 f32
  float* outp = (float*)d_out;

  k_qkv<<<dim3(32, 3, 8), 256, 0, stream>>>(x,
      kW, kb, kg, kbe, kmu, kva,
      qW, qb, qg, qbe, qmu, qva,
      vW, vb, vg, vbe, vmu, vva, qkv);
  k_denom<<<dim3(32), 256, 0, stream>>>(qkv, denom0);
  k_attn<<<dim3(32, 8), 256, 0, stream>>>(x, qkv, denom0, outp);
}

// Round 2
// 141.021 us; speedup vs baseline: 1.2576x; 1.2576x over previous
//
#include <hip/hip_runtime.h>

#define TDIM 2048

typedef __bf16 bf16_t;
typedef bf16_t bf16x8 __attribute__((ext_vector_type(8)));
typedef float f32x4 __attribute__((ext_vector_type(4)));
typedef unsigned short us8 __attribute__((ext_vector_type(8)));

__device__ __forceinline__ unsigned short f2bf(float x) {
  unsigned u = __builtin_bit_cast(unsigned, x);
  u += 0x7fffu + ((u >> 16) & 1u);            // round-to-nearest-even
  return (unsigned short)(u >> 16);
}

// ---------------------------------------------------------------------------
// K1: fused 1x1 conv + BN + ReLU.
//   gid 0 -> K (oc 0..63)  and Q (oc 64..127), written TRANSPOSED [b][t][64]
//   gid 1,2 -> V (oc 128..383), written [b][c][t]
// grid (32 t-tiles, 3 oc-groups, 8 batches), block 256
// ---------------------------------------------------------------------------
__global__ __launch_bounds__(256) void k_qkv(
    const float* __restrict__ x,
    const float* __restrict__ kW, const float* __restrict__ kb,
    const float* __restrict__ kg, const float* __restrict__ kbe,
    const float* __restrict__ kmu, const float* __restrict__ kva,
    const float* __restrict__ qW, const float* __restrict__ qb,
    const float* __restrict__ qg, const float* __restrict__ qbe,
    const float* __restrict__ qmu, const float* __restrict__ qva,
    const float* __restrict__ vW, const float* __restrict__ vb,
    const float* __restrict__ vg, const float* __restrict__ vbe,
    const float* __restrict__ vmu, const float* __restrict__ vva,
    unsigned short* __restrict__ vv,
    unsigned short* __restrict__ kT,
    unsigned short* __restrict__ qT)
{
  const int tb  = blockIdx.x;
  const int gid = blockIdx.y;
  const int b   = blockIdx.z;
  const int tid = threadIdx.x;
  const int lane = tid & 63, wv = tid >> 6;
  const int m = lane & 15, quad = lane >> 4;
  const int t0 = tb * 64;

  __shared__ unsigned short Ws[128 * 136];
  __shared__ unsigned short Xs[64 * 72];
  __shared__ float invs[128];
  __shared__ float effbs[128];

  if (tid < 128) {
    int G = gid * 128 + tid;
    float gg = (G < 64) ? kg[G]  : (G < 128) ? qg[G - 64]  : vg[G - 128];
    float vvv= (G < 64) ? kva[G] : (G < 128) ? qva[G - 64] : vva[G - 128];
    float bb = (G < 64) ? kb[G]  : (G < 128) ? qb[G - 64]  : vb[G - 128];
    float mm = (G < 64) ? kmu[G] : (G < 128) ? qmu[G - 64] : vmu[G - 128];
    float be = (G < 64) ? kbe[G] : (G < 128) ? qbe[G - 64] : vbe[G - 128];
    float inv = gg * rsqrtf(vvv + 1e-5f);
    invs[tid]  = inv;
    effbs[tid] = (bb - mm) * inv + be;
  }
  __syncthreads();

  const f32x4 fz = {0.f, 0.f, 0.f, 0.f};
  f32x4 acc[2][4];
#pragma unroll
  for (int i = 0; i < 2; ++i)
#pragma unroll
    for (int j = 0; j < 4; ++j) acc[i][j] = fz;

  for (int ch = 0; ch < 2; ++ch) {
    __syncthreads();
#pragma unroll 4
    for (int it = 0; it < 16; ++it) {
      int idx = it * 256 + tid;
      int row = idx >> 5;
      int c4  = (idx & 31) * 4;
      int G = gid * 128 + row;
      const float* Wp = (G < 64) ? (kW + G * 256)
                       : (G < 128) ? (qW + (G - 64) * 256)
                                   : (vW + (G - 128) * 256);
      float4 w4 = *(const float4*)(Wp + ch * 128 + c4);
      float inv = invs[row];
      ushort4 s4;
      s4.x = f2bf(w4.x * inv); s4.y = f2bf(w4.y * inv);
      s4.z = f2bf(w4.z * inv); s4.w = f2bf(w4.w * inv);
      *(ushort4*)&Ws[row * 136 + c4] = s4;
    }
    for (int cx = 0; cx < 2; ++cx) {
      __syncthreads();
      {
        int t  = tid & 63;
        int cb = b * 256 + ch * 128 + cx * 64;
#pragma unroll 4
        for (int i = 0; i < 16; ++i) {
          int c = i * 4 + (tid >> 6);
          float v = x[(size_t)(cb + c) * TDIM + t0 + t];
          int csw = (((c >> 3) ^ (t >> 3)) << 3) | (c & 7);
          Xs[t * 72 + csw] = f2bf(v);
        }
      }
      __syncthreads();
#pragma unroll
      for (int kk = 0; kk < 2; ++kk) {
        bf16x8 af[2];
#pragma unroll
        for (int mt = 0; mt < 2; ++mt) {
          int row = wv * 32 + mt * 16 + m;
          af[mt] = *(const bf16x8*)&Ws[row * 136 + cx * 64 + kk * 32 + quad * 8];
        }
#pragma unroll
        for (int nt = 0; nt < 4; ++nt) {
          int t = nt * 16 + m;
          int blk = (kk * 4 + quad) ^ (t >> 3);
          bf16x8 bfr = *(const bf16x8*)&Xs[t * 72 + blk * 8];
          acc[0][nt] = __builtin_amdgcn_mfma_f32_16x16x32_bf16(af[0], bfr, acc[0][nt], 0, 0, 0);
          acc[1][nt] = __builtin_amdgcn_mfma_f32_16x16x32_bf16(af[1], bfr, acc[1][nt], 0, 0, 0);
        }
      }
    }
  }
  // epilogue. D layout: row (oc) = quad*4+r, col (t) = m
  if (gid == 0) {
#pragma unroll
    for (int mt = 0; mt < 2; ++mt)
#pragma unroll
      for (int nt = 0; nt < 4; ++nt) {
        int ocl = wv * 32 + mt * 16 + quad * 4;
        int t = t0 + nt * 16 + m;
        ushort4 s4;
        float y0 = fmaxf(acc[mt][nt][0] + effbs[ocl + 0], 0.f);
        float y1 = fmaxf(acc[mt][nt][1] + effbs[ocl + 1], 0.f);
        float y2 = fmaxf(acc[mt][nt][2] + effbs[ocl + 2], 0.f);
        float y3 = fmaxf(acc[mt][nt][3] + effbs[ocl + 3], 0.f);
        s4.x = f2bf(y0); s4.y = f2bf(y1); s4.z = f2bf(y2); s4.w = f2bf(y3);
        unsigned short* dst = (ocl < 64)
            ? (kT + ((size_t)(b * TDIM + t)) * 64 + ocl)
            : (qT + ((size_t)(b * TDIM + t)) * 64 + (ocl - 64));
        *(ushort4*)dst = s4;
      }
  } else {
#pragma unroll
    for (int mt = 0; mt < 2; ++mt)
#pragma unroll
      for (int nt = 0; nt < 4; ++nt)
#pragma unroll
        for (int r = 0; r < 4; ++r) {
          int ocl = wv * 32 + mt * 16 + quad * 4 + r;
          float y = fmaxf(acc[mt][nt][r] + effbs[ocl], 0.f);
          int c = (gid - 1) * 128 + ocl;
          int t = t0 + nt * 16 + m;
          vv[(size_t)(b * 256 + c) * TDIM + t] = f2bf(y);
        }
  }
}

// ---------------------------------------------------------------------------
// K2: batch-0 row denominators (the reference's [0]-broadcast bug).
// grid 128 (16 rows each), block 512 (8 waves split the 17 s-tiles).
// ---------------------------------------------------------------------------
__global__ __launch_bounds__(512, 1) void k_denom(
    const unsigned short* __restrict__ kT,
    const unsigned short* __restrict__ qT,
    float* __restrict__ denom0)
{
  const int t0d = blockIdx.x * 16;
  const int tid = threadIdx.x;
  const int lane = tid & 63, w = tid >> 6;
  const int m = lane & 15, quad = lane >> 4;

  __shared__ unsigned short Qs[16 * 64];
  __shared__ unsigned short Ks[272 * 64];
  __shared__ float pmaxs[8][16];
  __shared__ float psums[8][16];

  // stage: 288 rows x 8 dblks, coalesced b128
  {
    const unsigned short* qg = qT + (size_t)t0d * 64;   // batch 0
#pragma unroll
    for (int it = 0; it < 5; ++it) {
      int idx = it * 512 + tid;
      if (idx < 2304) {
        int row = idx >> 3, dblk = idx & 7;
        us8 v = {0, 0, 0, 0, 0, 0, 0, 0};
        if (row < 16) {
          v = *(const us8*)(qg + row * 64 + dblk * 8);
          *(us8*)&Qs[row * 64 + ((dblk ^ (row & 7)) << 3)] = v;
        } else {
          int s = row - 16;
          int sg = t0d - 256 + s;
          if (sg >= 0) v = *(const us8*)(kT + (size_t)sg * 64 + dblk * 8);
          *(us8*)&Ks[s * 64 + ((dblk ^ (s & 7)) << 3)] = v;
        }
      }
    }
  }
  __syncthreads();

  const int jn = (w == 0) ? 3 : 2;
  f32x4 sc[3];
  {
    int t = m;
    bf16x8 qf0 = *(const bf16x8*)&Qs[t * 64 + ((quad ^ (t & 7)) << 3)];
    bf16x8 qf1 = *(const bf16x8*)&Qs[t * 64 + (((4 + quad) ^ (t & 7)) << 3)];
    const f32x4 fz = {0.f, 0.f, 0.f, 0.f};
#pragma unroll
    for (int jj = 0; jj < 3; ++jj) {
      if (jj < jn) {
        int j = w + jj * 8;
        int sr = 16 * j + m;
        f32x4 a = fz;
        bf16x8 kf0 = *(const bf16x8*)&Ks[sr * 64 + ((quad ^ (sr & 7)) << 3)];
        a = __builtin_amdgcn_mfma_f32_16x16x32_bf16(qf0, kf0, a, 0, 0, 0);
        bf16x8 kf1 = *(const bf16x8*)&Ks[sr * 64 + (((4 + quad) ^ (sr & 7)) << 3)];
        a = __builtin_amdgcn_mfma_f32_16x16x32_bf16(qf1, kf1, a, 0, 0, 0);
        sc[jj] = a;
      }
    }
  }

  float mx[4] = {0.f, 0.f, 0.f, 0.f};
#pragma unroll
  for (int jj = 0; jj < 3; ++jj)
    if (jj < jn) {
      int j = w + jj * 8;
#pragma unroll
      for (int r = 0; r < 4; ++r) {
        float v = sc[jj][r] * 0.125f;
        sc[jj][r] = v;
        int tg = t0d + quad * 4 + r;
        int sg = t0d - 256 + 16 * j + m;
        if (sg >= 0 && sg <= tg && tg - sg < 256) mx[r] = fmaxf(mx[r], v);
      }
    }
#pragma unroll
  for (int d = 1; d < 16; d <<= 1)
#pragma unroll
    for (int r = 0; r < 4; ++r) mx[r] = fmaxf(mx[r], __shfl_xor(mx[r], d, 64));
  if (m == 0)
#pragma unroll
    for (int r = 0; r < 4; ++r) pmaxs[w][quad * 4 + r] = mx[r];
  __syncthreads();

  float mxf[4];
#pragma unroll
  for (int r = 0; r < 4; ++r) {
    float v = pmaxs[0][quad * 4 + r];
#pragma unroll
    for (int ww = 1; ww < 8; ++ww) v = fmaxf(v, pmaxs[ww][quad * 4 + r]);
    mxf[r] = v;
  }
  float sm[4] = {0.f, 0.f, 0.f, 0.f};
#pragma unroll
  for (int jj = 0; jj < 3; ++jj)
    if (jj < jn) {
      int j = w + jj * 8;
#pragma unroll
      for (int r = 0; r < 4; ++r) {
        int tg = t0d + quad * 4 + r;
        int sg = t0d - 256 + 16 * j + m;
        if (sg >= 0 && sg <= tg && tg - sg < 256) sm[r] += __expf(sc[jj][r] - mxf[r]);
      }
    }
#pragma unroll
  for (int d = 1; d < 16; d <<= 1)
#pragma unroll
    for (int r = 0; r < 4; ++r) sm[r] += __shfl_xor(sm[r], d, 64);
  if (m == 0)
#pragma unroll
    for (int r = 0; r < 4; ++r) psums[w][quad * 4 + r] = sm[r];
  __syncthreads();

  if (tid < 16) {
    float s = 0.f;
#pragma unroll
    for (int ww = 0; ww < 8; ++ww) s += psums[ww][tid];
    denom0[t0d + tid] = s;
  }
}

// ---------------------------------------------------------------------------
// K3: banded attention + residual.
// grid (32 t-tiles, 2 c-halves, 8 batches), block 512 (8 waves).
// Score duplicated per c-half; PV uses per-wave private V staging (no barriers
// in the chunk loop; per-wave DS ops are in-order so WAR on Vsw is safe).
// ---------------------------------------------------------------------------
__global__ __launch_bounds__(512, 4) void k_attn(
    const float* __restrict__ x,
    const unsigned short* __restrict__ vv,
    const unsigned short* __restrict__ kT,
    const unsigned short* __restrict__ qT,
    const float* __restrict__ denom0,
    float* __restrict__ out)
{
  const int tb = blockIdx.x, ch = blockIdx.y, b = blockIdx.z;
  const int tid = threadIdx.x;
  const int lane = tid & 63, w = tid >> 6;
  const int m = lane & 15, quad = lane >> 4;
  const int t0 = tb * 64;

  // phase 1: Qs 64x64 (4096) + Ks 320x64 (20480) = 24576 shorts
  // phase 2: Ps 64x344 (22016) + Vs 8x(16x40) (5120) = 27136 shorts
  __shared__ unsigned short SM[27136];
  __shared__ float pmaxs[128];          // [half][row]
  unsigned short* Qs = SM;
  unsigned short* Ks = SM + 4096;
  unsigned short* Ps = SM;
  unsigned short* Vs = SM + 22016;

  // ---- stage Q (64 rows) + K band (320 rows), coalesced b128, swizzled ----
  {
    const unsigned short* qg  = qT + ((size_t)b * TDIM + t0) * 64;
    const unsigned short* kgb = kT + (size_t)b * TDIM * 64;
#pragma unroll
    for (int it = 0; it < 6; ++it) {
      int idx = it * 512 + tid;        // 0..3071
      int row = idx >> 3, dblk = idx & 7;
      us8 v = {0, 0, 0, 0, 0, 0, 0, 0};
      if (row < 64) {
        v = *(const us8*)(qg + row * 64 + dblk * 8);
        *(us8*)&Qs[row * 64 + ((dblk ^ (row & 7)) << 3)] = v;
      } else {
        int s = row - 64;
        int sg = t0 - 256 + s;
        if (sg >= 0) v = *(const us8*)(kgb + (size_t)sg * 64 + dblk * 8);
        *(us8*)&Ks[s * 64 + ((dblk ^ (s & 7)) << 3)] = v;
      }
    }
  }
  __syncthreads();

  // ---- score: wave w -> row-tile rt = w&3, s-half = w>>2 ----
  const int rt = w & 3, half = w >> 2;
  const int j0 = half ? 9 : 0;
  const int jn = half ? 8 : 9;
  f32x4 sc[9];
  {
    int t = rt * 16 + m;
    bf16x8 qf0 = *(const bf16x8*)&Qs[t * 64 + ((quad ^ (t & 7)) << 3)];
    bf16x8 qf1 = *(const bf16x8*)&Qs[t * 64 + (((4 + quad) ^ (t & 7)) << 3)];
    const f32x4 fz = {0.f, 0.f, 0.f, 0.f};
#pragma unroll
    for (int jj = 0; jj < 9; ++jj) {
      if (jj < jn) {
        int sr = 16 * (rt + j0 + jj) + m;
        f32x4 a = fz;
        bf16x8 kf0 = *(const bf16x8*)&Ks[sr * 64 + ((quad ^ (sr & 7)) << 3)];
        a = __builtin_amdgcn_mfma_f32_16x16x32_bf16(qf0, kf0, a, 0, 0, 0);
        bf16x8 kf1 = *(const bf16x8*)&Ks[sr * 64 + (((4 + quad) ^ (sr & 7)) << 3)];
        a = __builtin_amdgcn_mfma_f32_16x16x32_bf16(qf1, kf1, a, 0, 0, 0);
        sc[jj] = a;
      }
    }
  }

  const int tw = t0 + rt * 16;
  float mx[4] = {0.f, 0.f, 0.f, 0.f};
#pragma unroll
  for (int jj = 0; jj < 9; ++jj)
    if (jj < jn) {
#pragma unroll
      for (int r = 0; r < 4; ++r) {
        float v = sc[jj][r] * 0.125f;
        sc[jj][r] = v;
        int tg = tw + quad * 4 + r;
        int sg = t0 - 256 + 16 * (rt + j0 + jj) + m;
        if (sg >= 0 && sg <= tg && tg - sg < 256) mx[r] = fmaxf(mx[r], v);
      }
    }
#pragma unroll
  for (int d = 1; d < 16; d <<= 1)
#pragma unroll
    for (int r = 0; r < 4; ++r) mx[r] = fmaxf(mx[r], __shfl_xor(mx[r], d, 64));
  if (m == 0)
#pragma unroll
    for (int r = 0; r < 4; ++r) pmaxs[half * 64 + rt * 16 + quad * 4 + r] = mx[r];

  float dval[4];
#pragma unroll
  for (int r = 0; r < 4; ++r) dval[r] = denom0[tw + quad * 4 + r];

  __syncthreads();   // score frag reads + pmax writes complete

  // zero-fill Ps (aliases Qs/Ks) while reading combined max
  {
    us8 z = {0, 0, 0, 0, 0, 0, 0, 0};
#pragma unroll
    for (int it = 0; it < 6; ++it) {
      int idx = it * 512 + tid;       // 0..2751 us8-chunks
      if (idx < 2752) *(us8*)&Ps[idx * 8] = z;
    }
  }
  float mxf[4], rden[4];
#pragma unroll
  for (int r = 0; r < 4; ++r) {
    int row = rt * 16 + quad * 4 + r;
    mxf[r] = fmaxf(pmaxs[row], pmaxs[64 + row]);
    rden[r] = 1.f / (dval[r] + 1e-30f);
  }
#pragma unroll
  for (int jj = 0; jj < 9; ++jj)
    if (jj < jn) {
#pragma unroll
      for (int r = 0; r < 4; ++r) {
        int tg = tw + quad * 4 + r;
        int sg = t0 - 256 + 16 * (rt + j0 + jj) + m;
        bool ib = (sg >= 0 && sg <= tg && tg - sg < 256);
        sc[jj][r] = ib ? __expf(sc[jj][r] - mxf[r]) * rden[r] : 0.f;
      }
    }
  __syncthreads();   // zero-fill complete

  // scatter normalized P (rows rt*16+quad*4+r, cols 16*(rt+j)+m)
#pragma unroll
  for (int jj = 0; jj < 9; ++jj)
    if (jj < jn) {
      int col = 16 * (rt + j0 + jj) + m;
#pragma unroll
      for (int r = 0; r < 4; ++r)
        Ps[(rt * 16 + quad * 4 + r) * 344 + col] = f2bf(sc[jj][r]);
    }
  __syncthreads();   // P visible to all waves

  // ---- PV: wave w owns c-strip [ch*128 + w*16, +16); 10 chunks of 32 s ----
  const int cbase = ch * 128 + w * 16;
  unsigned short* Vsw = Vs + w * 640;   // 16 x 40 shorts
  const unsigned short* vg = vv + ((size_t)(b * 256 + cbase + (lane >> 2))) * TDIM;
  const int si = (lane & 3) * 8;
  const f32x4 fz = {0.f, 0.f, 0.f, 0.f};
  f32x4 acc[4] = {fz, fz, fz, fz};

  us8 vreg = {0, 0, 0, 0, 0, 0, 0, 0};
  {
    int sg = t0 - 256 + si;
    if (sg >= 0) vreg = *(const us8*)(vg + sg);
  }
#pragma unroll
  for (int chunk = 0; chunk < 10; ++chunk) {
    us8 vnext = {0, 0, 0, 0, 0, 0, 0, 0};
    if (chunk < 9) {
      int sg = t0 - 256 + (chunk + 1) * 32 + si;
      if (sg >= 0) vnext = *(const us8*)(vg + sg);
    }
    *(us8*)&Vsw[(lane >> 2) * 40 + si] = vreg;
    bf16x8 bfr = *(const bf16x8*)&Vsw[m * 40 + quad * 8];
#pragma unroll
    for (int mt = 0; mt < 4; ++mt) {
      bf16x8 af = *(const bf16x8*)&Ps[(mt * 16 + m) * 344 + chunk * 32 + quad * 8];
      acc[mt] = __builtin_amdgcn_mfma_f32_16x16x32_bf16(af, bfr, acc[mt], 0, 0, 0);
    }
    vreg = vnext;
  }

  // epilogue: out = x + O^T.  D: col (c) = m, row (t) = quad*4+r
#pragma unroll
  for (int mt = 0; mt < 4; ++mt) {
    int c = cbase + m;
    int t = t0 + mt * 16 + quad * 4;
    size_t off = (size_t)(b * 256 + c) * TDIM + t;
    float4 xv = *(const float4*)(x + off);
    float4 o;
    o.x = xv.x + acc[mt][0];
    o.y = xv.y + acc[mt][1];
    o.z = xv.z + acc[mt][2];
    o.w = xv.w + acc[mt][3];
    *(float4*)(out + off) = o;
  }
}

// ---------------------------------------------------------------------------
extern "C" void kernel_launch(void* const* d_in, const int* in_sizes, int n_in,
                              void* d_out, int out_size, void* d_ws, size_t ws_size,
                              hipStream_t stream) {
  const float* x   = (const float*)d_in[0];
  const float* kW  = (const float*)d_in[1];
  const float* kb  = (const float*)d_in[2];
  const float* kg  = (const float*)d_in[3];
  const float* kbe = (const float*)d_in[4];
  const float* kmu = (const float*)d_in[5];
  const float* kva = (const float*)d_in[6];
  const float* qW  = (const float*)d_in[7];
  const float* qb  = (const float*)d_in[8];
  const float* qg  = (const float*)d_in[9];
  const float* qbe = (const float*)d_in[10];
  const float* qmu = (const float*)d_in[11];
  const float* qva = (const float*)d_in[12];
  const float* vW  = (const float*)d_in[13];
  const float* vb  = (const float*)d_in[14];
  const float* vg  = (const float*)d_in[15];
  const float* vbe = (const float*)d_in[16];
  const float* vmu = (const float*)d_in[17];
  const float* vva = (const float*)d_in[18];

  unsigned short* vv  = (unsigned short*)d_ws;                  // 8 MB
  unsigned short* kTp = vv + (size_t)8 * 256 * TDIM;            // 2 MB
  unsigned short* qTp = kTp + (size_t)8 * TDIM * 64;            // 2 MB
  float* denom0 = (float*)(qTp + (size_t)8 * TDIM * 64);        // 8 KB
  float* outp = (float*)d_out;

  k_qkv<<<dim3(32, 3, 8), 256, 0, stream>>>(x,
      kW, kb, kg, kbe, kmu, kva,
      qW, qb, qg, qbe, qmu, qva,
      vW, vb, vg, vbe, vmu, vva, vv, kTp, qTp);
  k_denom<<<dim3(128), 512, 0, stream>>>(kTp, qTp, denom0);
  k_attn<<<dim3(32, 2, 8), 512, 0, stream>>>(x, vv, kTp, qTp, denom0, outp);
}

// Round 3
// 135.802 us; speedup vs baseline: 1.3060x; 1.0384x over previous
//
#include <hip/hip_runtime.h>

#define TDIM 2048

typedef __bf16 bf16_t;
typedef bf16_t bf16x8 __attribute__((ext_vector_type(8)));
typedef float f32x4 __attribute__((ext_vector_type(4)));
typedef unsigned short us8 __attribute__((ext_vector_type(8)));

__device__ __forceinline__ unsigned short f2bf(float x) {
  unsigned u = __builtin_bit_cast(unsigned, x);
  u += 0x7fffu + ((u >> 16) & 1u);            // round-to-nearest-even
  return (unsigned short)(u >> 16);
}

// async global->LDS, 16B per lane; lds must be wave-uniform, g is per-lane
__device__ __forceinline__ void gl_lds16(const unsigned short* g, unsigned short* l) {
  __builtin_amdgcn_global_load_lds(
      (const __attribute__((address_space(1))) unsigned int*)g,
      (__attribute__((address_space(3))) unsigned int*)l, 16, 0, 0);
}

// ---------------------------------------------------------------------------
// K0 (prep):
//   wg 0..255   : transpose x[b][c][t] f32 -> xTf bf16 in MFMA-fragment order
//                 xTf[(b*32+tb)*4+cc][f]*8, f = ((nt*8+cblk)*16+m), t=nt*16+m,
//                 c = cc*64+cblk*8+j  (frag = 8 consecutive c of one t)
//   wg 256..267 : BN-fold weights -> effWf bf16 fragment order
//                 effWf[(gid*4+cc)*1024+f]*8, f=((ocblk*8+cblk)*16+m),
//                 oc = gid*128+ocblk*16+m.  wg 256 also writes effb[384].
// ---------------------------------------------------------------------------
__global__ __launch_bounds__(256) void k_prep(
    const float* __restrict__ x,
    const float* __restrict__ kW, const float* __restrict__ kb,
    const float* __restrict__ kg, const float* __restrict__ kbe,
    const float* __restrict__ kmu, const float* __restrict__ kva,
    const float* __restrict__ qW, const float* __restrict__ qb,
    const float* __restrict__ qg, const float* __restrict__ qbe,
    const float* __restrict__ qmu, const float* __restrict__ qva,
    const float* __restrict__ vW, const float* __restrict__ vb,
    const float* __restrict__ vg, const float* __restrict__ vbe,
    const float* __restrict__ vmu, const float* __restrict__ vva,
    unsigned short* __restrict__ xTf,
    unsigned short* __restrict__ effWf,
    float* __restrict__ effb)
{
  const int w = blockIdx.x;
  const int tid = threadIdx.x;

  if (w < 256) {
    // ---- x transpose: 64t x 256c tile, 4 c-chunks through LDS ----
    const int tb = w & 31, b = w >> 5;
    const int t0 = tb * 64;
    __shared__ float Lf[64][66];
    for (int cc = 0; cc < 4; ++cc) {
      if (cc) __syncthreads();           // WAR on Lf
#pragma unroll
      for (int pass = 0; pass < 4; ++pass) {
        int cl = pass * 16 + (tid >> 4);
        int tp = (tid & 15) * 4;
        float4 vx = *(const float4*)(x + (size_t)(b * 256 + cc * 64 + cl) * TDIM + t0 + tp);
        Lf[cl][tp] = vx.x; Lf[cl][tp + 1] = vx.y;
        Lf[cl][tp + 2] = vx.z; Lf[cl][tp + 3] = vx.w;
      }
      __syncthreads();
      unsigned short* dst = xTf + (((size_t)(b * 32 + tb) * 4 + cc) * 512) * 8;
#pragma unroll
      for (int pass = 0; pass < 2; ++pass) {
        int f = pass * 256 + tid;
        int nt = f >> 7, cblk = (f >> 4) & 7, m = f & 15;
        int t = nt * 16 + m;
        ushort4 lo, hi;
        lo.x = f2bf(Lf[cblk * 8 + 0][t]); lo.y = f2bf(Lf[cblk * 8 + 1][t]);
        lo.z = f2bf(Lf[cblk * 8 + 2][t]); lo.w = f2bf(Lf[cblk * 8 + 3][t]);
        hi.x = f2bf(Lf[cblk * 8 + 4][t]); hi.y = f2bf(Lf[cblk * 8 + 5][t]);
        hi.z = f2bf(Lf[cblk * 8 + 6][t]); hi.w = f2bf(Lf[cblk * 8 + 7][t]);
        *(ushort4*)(dst + f * 8) = lo;
        *(ushort4*)(dst + f * 8 + 4) = hi;
      }
    }
  } else {
    // ---- weights ----
    const int idx = w - 256;            // gid*4 + cc
    const int gid = idx >> 2, cc = idx & 3;
    unsigned short* dst = effWf + (size_t)idx * 1024 * 8;
#pragma unroll
    for (int pass = 0; pass < 4; ++pass) {
      int f = pass * 256 + tid;
      int ocblk = f >> 7, cblk = (f >> 4) & 7, m = f & 15;
      int G = gid * 128 + ocblk * 16 + m;
      const float* Wp = (G < 64) ? (kW + G * 256)
                       : (G < 128) ? (qW + (G - 64) * 256)
                                   : (vW + (G - 128) * 256);
      float gg = (G < 64) ? kg[G]  : (G < 128) ? qg[G - 64]  : vg[G - 128];
      float vr = (G < 64) ? kva[G] : (G < 128) ? qva[G - 64] : vva[G - 128];
      float inv = gg * rsqrtf(vr + 1e-5f);
      int c = cc * 64 + cblk * 8;
      float4 a = *(const float4*)(Wp + c);
      float4 bq = *(const float4*)(Wp + c + 4);
      ushort4 lo, hi;
      lo.x = f2bf(a.x * inv);  lo.y = f2bf(a.y * inv);
      lo.z = f2bf(a.z * inv);  lo.w = f2bf(a.w * inv);
      hi.x = f2bf(bq.x * inv); hi.y = f2bf(bq.y * inv);
      hi.z = f2bf(bq.z * inv); hi.w = f2bf(bq.w * inv);
      *(ushort4*)(dst + f * 8) = lo;
      *(ushort4*)(dst + f * 8 + 4) = hi;
    }
    if (idx == 0) {
      for (int G = tid; G < 384; G += 256) {
        float gg = (G < 64) ? kg[G]  : (G < 128) ? qg[G - 64]  : vg[G - 128];
        float vr = (G < 64) ? kva[G] : (G < 128) ? qva[G - 64] : vva[G - 128];
        float bb = (G < 64) ? kb[G]  : (G < 128) ? qb[G - 64]  : vb[G - 128];
        float mm = (G < 64) ? kmu[G] : (G < 128) ? qmu[G - 64] : vmu[G - 128];
        float be = (G < 64) ? kbe[G] : (G < 128) ? qbe[G - 64] : vbe[G - 128];
        float inv = gg * rsqrtf(vr + 1e-5f);
        effb[G] = (bb - mm) * inv + be;
      }
    }
  }
}

// ---------------------------------------------------------------------------
// K1: QKV GEMM, pure bf16, global_load_lds staging, double-buffered K-chunks.
// grid (32 tb, 3 gid, 8 b) = 768 wgs (3/CU), block 256 (4 waves).
//   gid 0 -> K/Q written transposed [b][t][64]; gid 1,2 -> V [b][c][t]
// ---------------------------------------------------------------------------
__global__ __launch_bounds__(256, 3) void k_qkv(
    const unsigned short* __restrict__ effWf,
    const float* __restrict__ effb,
    const unsigned short* __restrict__ xTf,
    unsigned short* __restrict__ vv,
    unsigned short* __restrict__ kT,
    unsigned short* __restrict__ qT)
{
  const int tb = blockIdx.x, gid = blockIdx.y, b = blockIdx.z;
  const int tid = threadIdx.x;
  const int lane = tid & 63, wv = tid >> 6;
  const int m = lane & 15, quad = lane >> 4;
  const int t0 = tb * 64;

  __shared__ unsigned short Wb[2][8192];   // 128oc x 64c chunk, frag order
  __shared__ unsigned short Xb[2][4096];   // 64t x 64c chunk, frag order
  __shared__ float effbs[128];

  if (tid < 128) effbs[tid] = effb[gid * 128 + tid];

  const unsigned short* wbase = effWf + (size_t)gid * 4 * 1024 * 8;
  const unsigned short* xbase = xTf + ((size_t)(b * 32 + tb) * 4) * 512 * 8;

  auto stage = [&](int cc, int bufi) {
    const unsigned short* ws = wbase + (size_t)cc * 1024 * 8;
    const unsigned short* xs = xbase + (size_t)cc * 512 * 8;
#pragma unroll
    for (int i = 0; i < 4; ++i) {
      int ii = wv * 4 + i;
      gl_lds16(ws + (ii * 64 + lane) * 8, &Wb[bufi][ii * 512]);
    }
#pragma unroll
    for (int i = 0; i < 2; ++i) {
      int ii = wv * 2 + i;
      gl_lds16(xs + (ii * 64 + lane) * 8, &Xb[bufi][ii * 512]);
    }
  };

  const f32x4 fz = {0.f, 0.f, 0.f, 0.f};
  f32x4 acc[2][4];
#pragma unroll
  for (int i = 0; i < 2; ++i)
#pragma unroll
    for (int j = 0; j < 4; ++j) acc[i][j] = fz;

  stage(0, 0);
  for (int cc = 0; cc < 4; ++cc) {
    __syncthreads();                      // drains prev chunk's loads
    if (cc < 3) stage(cc + 1, (cc + 1) & 1);
    const unsigned short* Wc = Wb[cc & 1];
    const unsigned short* Xc = Xb[cc & 1];
#pragma unroll
    for (int kk = 0; kk < 2; ++kk) {
      int cb = kk * 4 + quad;
      bf16x8 af[2], bfv[4];
#pragma unroll
      for (int mt = 0; mt < 2; ++mt)
        af[mt] = *(const bf16x8*)&Wc[(((wv * 2 + mt) * 8 + cb) * 16 + m) * 8];
#pragma unroll
      for (int nt = 0; nt < 4; ++nt)
        bfv[nt] = *(const bf16x8*)&Xc[((nt * 8 + cb) * 16 + m) * 8];
#pragma unroll
      for (int mt = 0; mt < 2; ++mt)
#pragma unroll
        for (int nt = 0; nt < 4; ++nt)
          acc[mt][nt] = __builtin_amdgcn_mfma_f32_16x16x32_bf16(af[mt], bfv[nt], acc[mt][nt], 0, 0, 0);
    }
  }

  // epilogue. D layout: row (oc) = quad*4+r, col (t) = m
  if (gid == 0) {
#pragma unroll
    for (int mt = 0; mt < 2; ++mt)
#pragma unroll
      for (int nt = 0; nt < 4; ++nt) {
        int ocl = wv * 32 + mt * 16 + quad * 4;
        int t = t0 + nt * 16 + m;
        ushort4 s4;
        s4.x = f2bf(fmaxf(acc[mt][nt][0] + effbs[ocl + 0], 0.f));
        s4.y = f2bf(fmaxf(acc[mt][nt][1] + effbs[ocl + 1], 0.f));
        s4.z = f2bf(fmaxf(acc[mt][nt][2] + effbs[ocl + 2], 0.f));
        s4.w = f2bf(fmaxf(acc[mt][nt][3] + effbs[ocl + 3], 0.f));
        unsigned short* dst = (ocl < 64)
            ? (kT + ((size_t)(b * TDIM + t)) * 64 + ocl)
            : (qT + ((size_t)(b * TDIM + t)) * 64 + (ocl - 64));
        *(ushort4*)dst = s4;
      }
  } else {
#pragma unroll
    for (int mt = 0; mt < 2; ++mt)
#pragma unroll
      for (int nt = 0; nt < 4; ++nt)
#pragma unroll
        for (int r = 0; r < 4; ++r) {
          int ocl = wv * 32 + mt * 16 + quad * 4 + r;
          float y = fmaxf(acc[mt][nt][r] + effbs[ocl], 0.f);
          int c = (gid - 1) * 128 + ocl;
          int t = t0 + nt * 16 + m;
          vv[(size_t)(b * 256 + c) * TDIM + t] = f2bf(y);
        }
  }
}

// ---------------------------------------------------------------------------
// K2: batch-0 row denominators (the reference's [0]-broadcast bug).
// grid 128 (16 rows each), block 512 (8 waves split the 17 s-tiles).
// ---------------------------------------------------------------------------
__global__ __launch_bounds__(512, 1) void k_denom(
    const unsigned short* __restrict__ kT,
    const unsigned short* __restrict__ qT,
    float* __restrict__ denom0)
{
  const int t0d = blockIdx.x * 16;
  const int tid = threadIdx.x;
  const int lane = tid & 63, w = tid >> 6;
  const int m = lane & 15, quad = lane >> 4;

  __shared__ unsigned short Qs[16 * 64];
  __shared__ unsigned short Ks[272 * 64];
  __shared__ float pmaxs[8][16];
  __shared__ float psums[8][16];

  {
    const unsigned short* qg = qT + (size_t)t0d * 64;   // batch 0
#pragma unroll
    for (int it = 0; it < 5; ++it) {
      int idx = it * 512 + tid;
      if (idx < 2304) {
        int row = idx >> 3, dblk = idx & 7;
        us8 v = {0, 0, 0, 0, 0, 0, 0, 0};
        if (row < 16) {
          v = *(const us8*)(qg + row * 64 + dblk * 8);
          *(us8*)&Qs[row * 64 + ((dblk ^ (row & 7)) << 3)] = v;
        } else {
          int s = row - 16;
          int sg = t0d - 256 + s;
          if (sg >= 0) v = *(const us8*)(kT + (size_t)sg * 64 + dblk * 8);
          *(us8*)&Ks[s * 64 + ((dblk ^ (s & 7)) << 3)] = v;
        }
      }
    }
  }
  __syncthreads();

  const int jn = (w == 0) ? 3 : 2;
  f32x4 sc[3];
  {
    int t = m;
    bf16x8 qf0 = *(const bf16x8*)&Qs[t * 64 + ((quad ^ (t & 7)) << 3)];
    bf16x8 qf1 = *(const bf16x8*)&Qs[t * 64 + (((4 + quad) ^ (t & 7)) << 3)];
    const f32x4 fz = {0.f, 0.f, 0.f, 0.f};
#pragma unroll
    for (int jj = 0; jj < 3; ++jj) {
      if (jj < jn) {
        int j = w + jj * 8;
        int sr = 16 * j + m;
        f32x4 a = fz;
        bf16x8 kf0 = *(const bf16x8*)&Ks[sr * 64 + ((quad ^ (sr & 7)) << 3)];
        a = __builtin_amdgcn_mfma_f32_16x16x32_bf16(qf0, kf0, a, 0, 0, 0);
        bf16x8 kf1 = *(const bf16x8*)&Ks[sr * 64 + (((4 + quad) ^ (sr & 7)) << 3)];
        a = __builtin_amdgcn_mfma_f32_16x16x32_bf16(qf1, kf1, a, 0, 0, 0);
        sc[jj] = a;
      }
    }
  }

  float mx[4] = {0.f, 0.f, 0.f, 0.f};
#pragma unroll
  for (int jj = 0; jj < 3; ++jj)
    if (jj < jn) {
      int j = w + jj * 8;
#pragma unroll
      for (int r = 0; r < 4; ++r) {
        float v = sc[jj][r] * 0.125f;
        sc[jj][r] = v;
        int tg = t0d + quad * 4 + r;
        int sg = t0d - 256 + 16 * j + m;
        if (sg >= 0 && sg <= tg && tg - sg < 256) mx[r] = fmaxf(mx[r], v);
      }
    }
#pragma unroll
  for (int d = 1; d < 16; d <<= 1)
#pragma unroll
    for (int r = 0; r < 4; ++r) mx[r] = fmaxf(mx[r], __shfl_xor(mx[r], d, 64));
  if (m == 0)
#pragma unroll
    for (int r = 0; r < 4; ++r) pmaxs[w][quad * 4 + r] = mx[r];
  __syncthreads();

  float mxf[4];
#pragma unroll
  for (int r = 0; r < 4; ++r) {
    float v = pmaxs[0][quad * 4 + r];
#pragma unroll
    for (int ww = 1; ww < 8; ++ww) v = fmaxf(v, pmaxs[ww][quad * 4 + r]);
    mxf[r] = v;
  }
  float sm[4] = {0.f, 0.f, 0.f, 0.f};
#pragma unroll
  for (int jj = 0; jj < 3; ++jj)
    if (jj < jn) {
      int j = w + jj * 8;
#pragma unroll
      for (int r = 0; r < 4; ++r) {
        int tg = t0d + quad * 4 + r;
        int sg = t0d - 256 + 16 * j + m;
        if (sg >= 0 && sg <= tg && tg - sg < 256) sm[r] += __expf(sc[jj][r] - mxf[r]);
      }
    }
#pragma unroll
  for (int d = 1; d < 16; d <<= 1)
#pragma unroll
    for (int r = 0; r < 4; ++r) sm[r] += __shfl_xor(sm[r], d, 64);
  if (m == 0)
#pragma unroll
    for (int r = 0; r < 4; ++r) psums[w][quad * 4 + r] = sm[r];
  __syncthreads();

  if (tid < 16) {
    float s = 0.f;
#pragma unroll
    for (int ww = 0; ww < 8; ++ww) s += psums[ww][tid];
    denom0[t0d + tid] = s;
  }
}

// ---------------------------------------------------------------------------
// K3: banded attention + residual.
// grid (32 tb, 2 c-halves, 8 b), block 512 (8 waves).
// V fragments read DIRECTLY from global (16B contiguous in vv[c][t]) — no LDS.
// ---------------------------------------------------------------------------
__global__ __launch_bounds__(512, 4) void k_attn(
    const float* __restrict__ x,
    const unsigned short* __restrict__ vv,
    const unsigned short* __restrict__ kT,
    const unsigned short* __restrict__ qT,
    const float* __restrict__ denom0,
    float* __restrict__ out)
{
  const int tb = blockIdx.x, ch = blockIdx.y, b = blockIdx.z;
  const int tid = threadIdx.x;
  const int lane = tid & 63, w = tid >> 6;
  const int m = lane & 15, quad = lane >> 4;
  const int t0 = tb * 64;

  // phase 1: Qs 64x64 (4096) + Ks 320x64 (20480) = 24576 shorts
  // phase 2: Ps 64x344 (22016 shorts) aliases the same block
  __shared__ unsigned short SM[24576];
  __shared__ float pmaxs[128];          // [half][row]
  unsigned short* Qs = SM;
  unsigned short* Ks = SM + 4096;
  unsigned short* Ps = SM;

  {
    const unsigned short* qg  = qT + ((size_t)b * TDIM + t0) * 64;
    const unsigned short* kgb = kT + (size_t)b * TDIM * 64;
#pragma unroll
    for (int it = 0; it < 6; ++it) {
      int idx = it * 512 + tid;        // 0..3071
      int row = idx >> 3, dblk = idx & 7;
      us8 v = {0, 0, 0, 0, 0, 0, 0, 0};
      if (row < 64) {
        v = *(const us8*)(qg + row * 64 + dblk * 8);
        *(us8*)&Qs[row * 64 + ((dblk ^ (row & 7)) << 3)] = v;
      } else {
        int s = row - 64;
        int sg = t0 - 256 + s;
        if (sg >= 0) v = *(const us8*)(kgb + (size_t)sg * 64 + dblk * 8);
        *(us8*)&Ks[s * 64 + ((dblk ^ (s & 7)) << 3)] = v;
      }
    }
  }
  __syncthreads();

  // ---- score: wave w -> row-tile rt = w&3, s-half = w>>2 ----
  const int rt = w & 3, half = w >> 2;
  const int j0 = half ? 9 : 0;
  const int jn = half ? 8 : 9;
  f32x4 sc[9];
  {
    int t = rt * 16 + m;
    bf16x8 qf0 = *(const bf16x8*)&Qs[t * 64 + ((quad ^ (t & 7)) << 3)];
    bf16x8 qf1 = *(const bf16x8*)&Qs[t * 64 + (((4 + quad) ^ (t & 7)) << 3)];
    const f32x4 fz = {0.f, 0.f, 0.f, 0.f};
#pragma unroll
    for (int jj = 0; jj < 9; ++jj) {
      if (jj < jn) {
        int sr = 16 * (rt + j0 + jj) + m;
        f32x4 a = fz;
        bf16x8 kf0 = *(const bf16x8*)&Ks[sr * 64 + ((quad ^ (sr & 7)) << 3)];
        a = __builtin_amdgcn_mfma_f32_16x16x32_bf16(qf0, kf0, a, 0, 0, 0);
        bf16x8 kf1 = *(const bf16x8*)&Ks[sr * 64 + (((4 + quad) ^ (sr & 7)) << 3)];
        a = __builtin_amdgcn_mfma_f32_16x16x32_bf16(qf1, kf1, a, 0, 0, 0);
        sc[jj] = a;
      }
    }
  }

  const int tw = t0 + rt * 16;
  float mx[4] = {0.f, 0.f, 0.f, 0.f};
#pragma unroll
  for (int jj = 0; jj < 9; ++jj)
    if (jj < jn) {
#pragma unroll
      for (int r = 0; r < 4; ++r) {
        float v = sc[jj][r] * 0.125f;
        sc[jj][r] = v;
        int tg = tw + quad * 4 + r;
        int sg = t0 - 256 + 16 * (rt + j0 + jj) + m;
        if (sg >= 0 && sg <= tg && tg - sg < 256) mx[r] = fmaxf(mx[r], v);
      }
    }
#pragma unroll
  for (int d = 1; d < 16; d <<= 1)
#pragma unroll
    for (int r = 0; r < 4; ++r) mx[r] = fmaxf(mx[r], __shfl_xor(mx[r], d, 64));
  if (m == 0)
#pragma unroll
    for (int r = 0; r < 4; ++r) pmaxs[half * 64 + rt * 16 + quad * 4 + r] = mx[r];

  float dval[4];
#pragma unroll
  for (int r = 0; r < 4; ++r) dval[r] = denom0[tw + quad * 4 + r];

  __syncthreads();   // score frag reads + pmax writes complete

  // zero-fill Ps (aliases Qs/Ks) while reading combined max
  {
    us8 z = {0, 0, 0, 0, 0, 0, 0, 0};
#pragma unroll
    for (int it = 0; it < 6; ++it) {
      int idx = it * 512 + tid;       // 0..2751 us8-chunks
      if (idx < 2752) *(us8*)&Ps[idx * 8] = z;
    }
  }
  float mxf[4], rden[4];
#pragma unroll
  for (int r = 0; r < 4; ++r) {
    int row = rt * 16 + quad * 4 + r;
    mxf[r] = fmaxf(pmaxs[row], pmaxs[64 + row]);
    rden[r] = 1.f / (dval[r] + 1e-30f);
  }
#pragma unroll
  for (int jj = 0; jj < 9; ++jj)
    if (jj < jn) {
#pragma unroll
      for (int r = 0; r < 4; ++r) {
        int tg = tw + quad * 4 + r;
        int sg = t0 - 256 + 16 * (rt + j0 + jj) + m;
        bool ib = (sg >= 0 && sg <= tg && tg - sg < 256);
        sc[jj][r] = ib ? __expf(sc[jj][r] - mxf[r]) * rden[r] : 0.f;
      }
    }
  __syncthreads();   // zero-fill complete

  // scatter normalized P (rows rt*16+quad*4+r, cols 16*(rt+j)+m)
#pragma unroll
  for (int jj = 0; jj < 9; ++jj)
    if (jj < jn) {
      int col = 16 * (rt + j0 + jj) + m;
#pragma unroll
      for (int r = 0; r < 4; ++r)
        Ps[(rt * 16 + quad * 4 + r) * 344 + col] = f2bf(sc[jj][r]);
    }
  __syncthreads();   // P visible to all waves

  // ---- PV: wave w owns c-strip [ch*128 + w*16, +16); V frags from global ----
  const int cbase = ch * 128 + w * 16;
  const unsigned short* vrow = vv + (size_t)(b * 256 + cbase + m) * TDIM;
  const f32x4 fz = {0.f, 0.f, 0.f, 0.f};
  f32x4 acc[4] = {fz, fz, fz, fz};

  us8 vreg = {0, 0, 0, 0, 0, 0, 0, 0};
  if (t0 >= 256) vreg = *(const us8*)(vrow + t0 - 256 + quad * 8);
#pragma unroll
  for (int chunk = 0; chunk < 10; ++chunk) {
    us8 vnext = {0, 0, 0, 0, 0, 0, 0, 0};
    if (chunk < 9) {
      int sbase = t0 - 256 + (chunk + 1) * 32;
      if (sbase >= 0) vnext = *(const us8*)(vrow + sbase + quad * 8);
    }
    bf16x8 bfr = __builtin_bit_cast(bf16x8, vreg);
#pragma unroll
    for (int mt = 0; mt < 4; ++mt) {
      bf16x8 af = *(const bf16x8*)&Ps[(mt * 16 + m) * 344 + chunk * 32 + quad * 8];
      acc[mt] = __builtin_amdgcn_mfma_f32_16x16x32_bf16(af, bfr, acc[mt], 0, 0, 0);
    }
    vreg = vnext;
  }

  // epilogue: out = x + O^T.  D: col (c) = m, row (t) = quad*4+r
#pragma unroll
  for (int mt = 0; mt < 4; ++mt) {
    int c = cbase + m;
    int t = t0 + mt * 16 + quad * 4;
    size_t off = (size_t)(b * 256 + c) * TDIM + t;
    float4 xv = *(const float4*)(x + off);
    float4 o;
    o.x = xv.x + acc[mt][0];
    o.y = xv.y + acc[mt][1];
    o.z = xv.z + acc[mt][2];
    o.w = xv.w + acc[mt][3];
    *(float4*)(out + off) = o;
  }
}

// ---------------------------------------------------------------------------
extern "C" void kernel_launch(void* const* d_in, const int* in_sizes, int n_in,
                              void* d_out, int out_size, void* d_ws, size_t ws_size,
                              hipStream_t stream) {
  const float* x   = (const float*)d_in[0];
  const float* kW  = (const float*)d_in[1];
  const float* kb  = (const float*)d_in[2];
  const float* kg  = (const float*)d_in[3];
  const float* kbe = (const float*)d_in[4];
  const float* kmu = (const float*)d_in[5];
  const float* kva = (const float*)d_in[6];
  const float* qW  = (const float*)d_in[7];
  const float* qb  = (const float*)d_in[8];
  const float* qg  = (const float*)d_in[9];
  const float* qbe = (const float*)d_in[10];
  const float* qmu = (const float*)d_in[11];
  const float* qva = (const float*)d_in[12];
  const float* vW  = (const float*)d_in[13];
  const float* vb  = (const float*)d_in[14];
  const float* vg  = (const float*)d_in[15];
  const float* vbe = (const float*)d_in[16];
  const float* vmu = (const float*)d_in[17];
  const float* vva = (const float*)d_in[18];

  unsigned short* vv  = (unsigned short*)d_ws;                  // 8 MB
  unsigned short* kTp = vv + (size_t)8 * 256 * TDIM;            // 2 MB
  unsigned short* qTp = kTp + (size_t)8 * TDIM * 64;            // 2 MB
  float* denom0 = (float*)(qTp + (size_t)8 * TDIM * 64);        // 8 KB
  unsigned short* xTf = (unsigned short*)(denom0 + 2048);       // 8.4 MB
  unsigned short* effWf = xTf + (size_t)8 * 256 * TDIM;         // 192 KB
  float* effb = (float*)(effWf + 384 * 256);                    // 1.5 KB
  float* outp = (float*)d_out;

  k_prep<<<dim3(268), 256, 0, stream>>>(x,
      kW, kb, kg, kbe, kmu, kva,
      qW, qb, qg, qbe, qmu, qva,
      vW, vb, vg, vbe, vmu, vva, xTf, effWf, effb);
  k_qkv<<<dim3(32, 3, 8), 256, 0, stream>>>(effWf, effb, xTf, vv, kTp, qTp);
  k_denom<<<dim3(128), 512, 0, stream>>>(kTp, qTp, denom0);
  k_attn<<<dim3(32, 2, 8), 512, 0, stream>>>(x, vv, kTp, qTp, denom0, outp);
}

// Round 4
// 133.659 us; speedup vs baseline: 1.3269x; 1.0160x over previous
//
#include <hip/hip_runtime.h>

#define TDIM 2048

typedef __bf16 bf16_t;
typedef bf16_t bf16x8 __attribute__((ext_vector_type(8)));
typedef float f32x4 __attribute__((ext_vector_type(4)));
typedef unsigned short us8 __attribute__((ext_vector_type(8)));

__device__ __forceinline__ unsigned short f2bf(float x) {
  unsigned u = __builtin_bit_cast(unsigned, x);
  u += 0x7fffu + ((u >> 16) & 1u);            // round-to-nearest-even
  return (unsigned short)(u >> 16);
}

// async global->LDS, 16B per lane; lds base wave-uniform (HW adds lane*16)
__device__ __forceinline__ void gl_lds16(const unsigned short* g, unsigned short* l) {
  __builtin_amdgcn_global_load_lds(
      (const __attribute__((address_space(1))) unsigned int*)g,
      (__attribute__((address_space(3))) unsigned int*)l, 16, 0, 0);
}

// ---------------------------------------------------------------------------
// K0: BN-fold weights -> effWf bf16 in MFMA-fragment order. grid 12 x 256.
//   effWf[idx=(gid*4+cc)][f]*8, f=((ocblk*8+cblk)*16+m), oc=gid*128+ocblk*16+m,
//   c = cc*64+cblk*8+j.  wg 0 also writes effb[384].
// ---------------------------------------------------------------------------
__global__ __launch_bounds__(256) void k_prepw(
    const float* __restrict__ kW, const float* __restrict__ kb,
    const float* __restrict__ kg, const float* __restrict__ kbe,
    const float* __restrict__ kmu, const float* __restrict__ kva,
    const float* __restrict__ qW, const float* __restrict__ qb,
    const float* __restrict__ qg, const float* __restrict__ qbe,
    const float* __restrict__ qmu, const float* __restrict__ qva,
    const float* __restrict__ vW, const float* __restrict__ vb,
    const float* __restrict__ vg, const float* __restrict__ vbe,
    const float* __restrict__ vmu, const float* __restrict__ vva,
    unsigned short* __restrict__ effWf,
    float* __restrict__ effb)
{
  const int idx = blockIdx.x;            // gid*4 + cc
  const int tid = threadIdx.x;
  const int gid = idx >> 2, cc = idx & 3;
  unsigned short* dst = effWf + (size_t)idx * 8192;
#pragma unroll
  for (int pass = 0; pass < 4; ++pass) {
    int f = pass * 256 + tid;
    int ocblk = f >> 7, cblk = (f >> 4) & 7, m = f & 15;
    int G = gid * 128 + ocblk * 16 + m;
    const float* Wp = (G < 64) ? (kW + G * 256)
                     : (G < 128) ? (qW + (G - 64) * 256)
                                 : (vW + (G - 128) * 256);
    float gg = (G < 64) ? kg[G]  : (G < 128) ? qg[G - 64]  : vg[G - 128];
    float vr = (G < 64) ? kva[G] : (G < 128) ? qva[G - 64] : vva[G - 128];
    float inv = gg * rsqrtf(vr + 1e-5f);
    int c = cc * 64 + cblk * 8;
    float4 a = *(const float4*)(Wp + c);
    float4 bq = *(const float4*)(Wp + c + 4);
    ushort4 lo, hi;
    lo.x = f2bf(a.x * inv);  lo.y = f2bf(a.y * inv);
    lo.z = f2bf(a.z * inv);  lo.w = f2bf(a.w * inv);
    hi.x = f2bf(bq.x * inv); hi.y = f2bf(bq.y * inv);
    hi.z = f2bf(bq.z * inv); hi.w = f2bf(bq.w * inv);
    *(ushort4*)(dst + f * 8) = lo;
    *(ushort4*)(dst + f * 8 + 4) = hi;
  }
  if (idx == 0) {
    for (int G = tid; G < 384; G += 256) {
      float gg = (G < 64) ? kg[G]  : (G < 128) ? qg[G - 64]  : vg[G - 128];
      float vr = (G < 64) ? kva[G] : (G < 128) ? qva[G - 64] : vva[G - 128];
      float bb = (G < 64) ? kb[G]  : (G < 128) ? qb[G - 64]  : vb[G - 128];
      float mm = (G < 64) ? kmu[G] : (G < 128) ? qmu[G - 64] : vmu[G - 128];
      float be = (G < 64) ? kbe[G] : (G < 128) ? qbe[G - 64] : vbe[G - 128];
      float inv = gg * rsqrtf(vr + 1e-5f);
      effb[G] = (bb - mm) * inv + be;
    }
  }
}

// ---------------------------------------------------------------------------
// K1: QKV GEMM. W via global_load_lds (frag order), x transposed inline.
// grid (32 tb, 3 gid, 8 b), block 256 (4 waves), 3 wg/CU.
//   gid 0 -> K/Q written transposed+PRE-SWIZZLED [b][t][64']:
//            col' = ((ocblk ^ (t&7))<<3) | (oc&7)
//   gid 1,2 -> V [b][c][t]
// ---------------------------------------------------------------------------
__global__ __launch_bounds__(256, 3) void k_qkv(
    const unsigned short* __restrict__ effWf,
    const float* __restrict__ effb,
    const float* __restrict__ x,
    unsigned short* __restrict__ vv,
    unsigned short* __restrict__ kTs,
    unsigned short* __restrict__ qTs)
{
  const int tb = blockIdx.x, gid = blockIdx.y, b = blockIdx.z;
  const int tid = threadIdx.x;
  const int lane = tid & 63, wv = tid >> 6;
  const int m = lane & 15, quad = lane >> 4;
  const int t0 = tb * 64;

  __shared__ unsigned short Wb[2][8192];   // 128oc x 64c chunk, frag order
  __shared__ unsigned short Xs[4608];      // 64t x 64c, XOR-swizzled (72 pitch)
  __shared__ float effbs[128];

  if (tid < 128) effbs[tid] = effb[gid * 128 + tid];

  const unsigned short* wbase = effWf + (size_t)gid * 32768;
  const float* xb = x + (size_t)b * 256 * TDIM + t0 + lane;

  float xr[16];

  auto stageW = [&](int cc, int bufi) {
    const unsigned short* ws = wbase + cc * 8192;
#pragma unroll
    for (int i = 0; i < 4; ++i) {
      int ii = wv * 4 + i;
      gl_lds16(ws + (ii * 64 + lane) * 8, &Wb[bufi][ii * 512]);
    }
  };
  auto loadX = [&](int cc) {
#pragma unroll
    for (int p = 0; p < 4; ++p)
#pragma unroll
      for (int j = 0; j < 4; ++j) {
        int c = cc * 64 + p * 16 + wv * 4 + j;
        xr[p * 4 + j] = xb[(size_t)c * TDIM];
      }
  };

  const f32x4 fz = {0.f, 0.f, 0.f, 0.f};
  f32x4 acc[2][4];
#pragma unroll
  for (int i = 0; i < 2; ++i)
#pragma unroll
    for (int j = 0; j < 4; ++j) acc[i][j] = fz;

  stageW(0, 0);
  loadX(0);
  for (int cc = 0; cc < 4; ++cc) {
    __syncthreads();                 // drains W(cc) glds; Xs WAR safe
    // transpose-convert x chunk into Xs
#pragma unroll
    for (int p = 0; p < 4; ++p) {
      int cb4 = p * 16 + wv * 4;     // aligned 4, (cb4&7) in {0,4}
      int swz = (((cb4 >> 3) ^ (lane >> 3)) << 3) | (cb4 & 7);
      ushort4 s4;
      s4.x = f2bf(xr[p * 4 + 0]); s4.y = f2bf(xr[p * 4 + 1]);
      s4.z = f2bf(xr[p * 4 + 2]); s4.w = f2bf(xr[p * 4 + 3]);
      *(ushort4*)&Xs[lane * 72 + swz] = s4;
    }
    if (cc < 3) { stageW(cc + 1, (cc + 1) & 1); loadX(cc + 1); }
    __syncthreads();                 // Xs visible
    const unsigned short* Wc = Wb[cc & 1];
#pragma unroll
    for (int kk = 0; kk < 2; ++kk) {
      int cb = kk * 4 + quad;
      bf16x8 af[2], bfv[4];
#pragma unroll
      for (int mt = 0; mt < 2; ++mt)
        af[mt] = *(const bf16x8*)&Wc[(((wv * 2 + mt) * 8 + cb) * 16 + m) * 8];
#pragma unroll
      for (int nt = 0; nt < 4; ++nt) {
        int t = nt * 16 + m;
        bfv[nt] = *(const bf16x8*)&Xs[t * 72 + ((cb ^ (t >> 3)) << 3)];
      }
#pragma unroll
      for (int mt = 0; mt < 2; ++mt)
#pragma unroll
        for (int nt = 0; nt < 4; ++nt)
          acc[mt][nt] = __builtin_amdgcn_mfma_f32_16x16x32_bf16(af[mt], bfv[nt], acc[mt][nt], 0, 0, 0);
    }
  }

  // epilogue. D layout: row (oc) = quad*4+r, col (t) = m
  if (gid == 0) {
#pragma unroll
    for (int mt = 0; mt < 2; ++mt)
#pragma unroll
      for (int nt = 0; nt < 4; ++nt) {
        int ocl = wv * 32 + mt * 16 + quad * 4;
        int t = t0 + nt * 16 + m;
        ushort4 s4;
        s4.x = f2bf(fmaxf(acc[mt][nt][0] + effbs[ocl + 0], 0.f));
        s4.y = f2bf(fmaxf(acc[mt][nt][1] + effbs[ocl + 1], 0.f));
        s4.z = f2bf(fmaxf(acc[mt][nt][2] + effbs[ocl + 2], 0.f));
        s4.w = f2bf(fmaxf(acc[mt][nt][3] + effbs[ocl + 3], 0.f));
        if (ocl < 64) {
          int col = (((ocl >> 3) ^ (t & 7)) << 3) | (ocl & 7);
          *(ushort4*)(kTs + ((size_t)(b * TDIM + t)) * 64 + col) = s4;
        } else {
          int oq = ocl - 64;
          int col = (((oq >> 3) ^ (t & 7)) << 3) | (oq & 7);
          *(ushort4*)(qTs + ((size_t)(b * TDIM + t)) * 64 + col) = s4;
        }
      }
  } else {
#pragma unroll
    for (int mt = 0; mt < 2; ++mt)
#pragma unroll
      for (int nt = 0; nt < 4; ++nt)
#pragma unroll
        for (int r = 0; r < 4; ++r) {
          int ocl = wv * 32 + mt * 16 + quad * 4 + r;
          float y = fmaxf(acc[mt][nt][r] + effbs[ocl], 0.f);
          int c = (gid - 1) * 128 + ocl;
          int t = t0 + nt * 16 + m;
          vv[(size_t)(b * 256 + c) * TDIM + t] = f2bf(y);
        }
  }
}

// ---------------------------------------------------------------------------
// K2: batch-0 row denominators (the reference's [0]-broadcast bug).
// grid 128 (16 rows each), block 512 (8 waves split the 17 s-tiles).
// Staging = pure linear global_load_lds copy (kTs/qTs are pre-swizzled).
// ---------------------------------------------------------------------------
__global__ __launch_bounds__(512, 1) void k_denom(
    const unsigned short* __restrict__ kTs,
    const unsigned short* __restrict__ qTs,
    float* __restrict__ denom0)
{
  const int t0d = blockIdx.x * 16;
  const int tid = threadIdx.x;
  const int lane = tid & 63, w = tid >> 6;
  const int m = lane & 15, quad = lane >> 4;

  __shared__ unsigned short S[18432];     // Qs 16x64 | Ks 272x64
  unsigned short* Qs = S;
  unsigned short* Ks = S + 1024;
  __shared__ float pmaxs[8][16];
  __shared__ float psums[8][16];

  {
    const unsigned short* qg = qTs + (size_t)t0d * 64;
    const unsigned short* kg = kTs + ((long)t0d - 256) * 64;  // may dip into vv: finite, masked
#pragma unroll
    for (int it = 0; it < 5; ++it) {
      int j = it * 512 + tid;
      if (j < 2304) {                     // wave-uniform (it==4 -> waves 0..3)
        const unsigned short* g = (j < 128) ? (qg + j * 8) : (kg + (size_t)(j - 128) * 8);
        gl_lds16(g, &S[(it * 512 + w * 64) * 8]);
      }
    }
  }
  __syncthreads();

  const int jn = (w == 0) ? 3 : 2;
  f32x4 sc[3];
  {
    int t = m;
    bf16x8 qf0 = *(const bf16x8*)&Qs[t * 64 + ((quad ^ (t & 7)) << 3)];
    bf16x8 qf1 = *(const bf16x8*)&Qs[t * 64 + (((4 + quad) ^ (t & 7)) << 3)];
    const f32x4 fz = {0.f, 0.f, 0.f, 0.f};
#pragma unroll
    for (int jj = 0; jj < 3; ++jj) {
      if (jj < jn) {
        int j = w + jj * 8;
        int sr = 16 * j + m;
        f32x4 a = fz;
        bf16x8 kf0 = *(const bf16x8*)&Ks[sr * 64 + ((quad ^ (sr & 7)) << 3)];
        a = __builtin_amdgcn_mfma_f32_16x16x32_bf16(qf0, kf0, a, 0, 0, 0);
        bf16x8 kf1 = *(const bf16x8*)&Ks[sr * 64 + (((4 + quad) ^ (sr & 7)) << 3)];
        a = __builtin_amdgcn_mfma_f32_16x16x32_bf16(qf1, kf1, a, 0, 0, 0);
        sc[jj] = a;
      }
    }
  }

  float mx[4] = {0.f, 0.f, 0.f, 0.f};
#pragma unroll
  for (int jj = 0; jj < 3; ++jj)
    if (jj < jn) {
      int j = w + jj * 8;
#pragma unroll
      for (int r = 0; r < 4; ++r) {
        float v = sc[jj][r] * 0.125f;
        sc[jj][r] = v;
        int tg = t0d + quad * 4 + r;
        int sg = t0d - 256 + 16 * j + m;
        if (sg >= 0 && sg <= tg && tg - sg < 256) mx[r] = fmaxf(mx[r], v);
      }
    }
#pragma unroll
  for (int d = 1; d < 16; d <<= 1)
#pragma unroll
    for (int r = 0; r < 4; ++r) mx[r] = fmaxf(mx[r], __shfl_xor(mx[r], d, 64));
  if (m == 0)
#pragma unroll
    for (int r = 0; r < 4; ++r) pmaxs[w][quad * 4 + r] = mx[r];
  __syncthreads();

  float mxf[4];
#pragma unroll
  for (int r = 0; r < 4; ++r) {
    float v = pmaxs[0][quad * 4 + r];
#pragma unroll
    for (int ww = 1; ww < 8; ++ww) v = fmaxf(v, pmaxs[ww][quad * 4 + r]);
    mxf[r] = v;
  }
  float sm[4] = {0.f, 0.f, 0.f, 0.f};
#pragma unroll
  for (int jj = 0; jj < 3; ++jj)
    if (jj < jn) {
      int j = w + jj * 8;
#pragma unroll
      for (int r = 0; r < 4; ++r) {
        int tg = t0d + quad * 4 + r;
        int sg = t0d - 256 + 16 * j + m;
        if (sg >= 0 && sg <= tg && tg - sg < 256) sm[r] += __expf(sc[jj][r] - mxf[r]);
      }
    }
#pragma unroll
  for (int d = 1; d < 16; d <<= 1)
#pragma unroll
    for (int r = 0; r < 4; ++r) sm[r] += __shfl_xor(sm[r], d, 64);
  if (m == 0)
#pragma unroll
    for (int r = 0; r < 4; ++r) psums[w][quad * 4 + r] = sm[r];
  __syncthreads();

  if (tid < 16) {
    float s = 0.f;
#pragma unroll
    for (int ww = 0; ww < 8; ++ww) s += psums[ww][tid];
    denom0[t0d + tid] = s;
  }
}

// ---------------------------------------------------------------------------
// K3: banded attention + residual.
// grid (32 tb, 2 ch, 8 b), block 512 (8 waves). 3 barriers.
// Staging = linear global_load_lds; P zero-PADS instead of full zero-fill;
// PV windows of 9 chunks per row-tile; V frags direct from global.
// ---------------------------------------------------------------------------
__global__ __launch_bounds__(512, 4) void k_attn(
    const float* __restrict__ x,
    const unsigned short* __restrict__ vv,
    const unsigned short* __restrict__ kTs,
    const unsigned short* __restrict__ qTs,
    const float* __restrict__ denom0,
    float* __restrict__ out)
{
  const int tb = blockIdx.x, ch = blockIdx.y, b = blockIdx.z;
  const int tid = threadIdx.x;
  const int lane = tid & 63, w = tid >> 6;
  const int m = lane & 15, quad = lane >> 4;
  const int t0 = tb * 64;

  // phase 1: Qs 64x64 (4096) + Ks 320x64 (20480); phase 2: Ps 64x344 (22016)
  __shared__ unsigned short SM[24576];
  __shared__ float pmaxs[128];          // [half][row]
  unsigned short* Qs = SM;
  unsigned short* Ks = SM + 4096;
  unsigned short* Ps = SM;

  {
    const unsigned short* qg = qTs + ((size_t)(b * TDIM + t0)) * 64;
    const unsigned short* kg = kTs + ((long)(b * TDIM + t0) - 256) * 64;  // finite garbage ok, masked
#pragma unroll
    for (int it = 0; it < 6; ++it) {
      int j = it * 512 + tid;
      const unsigned short* g = (j < 512) ? (qg + (size_t)j * 8)
                                          : (kg + (size_t)(j - 512) * 8);
      gl_lds16(g, &SM[(it * 512 + w * 64) * 8]);
    }
  }
  const int rt = w & 3, half = w >> 2;
  const int tw = t0 + rt * 16;
  float dval[4];
#pragma unroll
  for (int r = 0; r < 4; ++r) dval[r] = denom0[tw + quad * 4 + r];
  __syncthreads();                       // B1: staging drained

  const int j0 = half ? 9 : 0;
  const int jn = half ? 8 : 9;
  f32x4 sc[9];
  {
    int t = rt * 16 + m;
    bf16x8 qf0 = *(const bf16x8*)&Qs[t * 64 + ((quad ^ (t & 7)) << 3)];
    bf16x8 qf1 = *(const bf16x8*)&Qs[t * 64 + (((4 + quad) ^ (t & 7)) << 3)];
    const f32x4 fz = {0.f, 0.f, 0.f, 0.f};
#pragma unroll
    for (int jj = 0; jj < 9; ++jj) {
      if (jj < jn) {
        int sr = 16 * (rt + j0 + jj) + m;
        f32x4 a = fz;
        bf16x8 kf0 = *(const bf16x8*)&Ks[sr * 64 + ((quad ^ (sr & 7)) << 3)];
        a = __builtin_amdgcn_mfma_f32_16x16x32_bf16(qf0, kf0, a, 0, 0, 0);
        bf16x8 kf1 = *(const bf16x8*)&Ks[sr * 64 + (((4 + quad) ^ (sr & 7)) << 3)];
        a = __builtin_amdgcn_mfma_f32_16x16x32_bf16(qf1, kf1, a, 0, 0, 0);
        sc[jj] = a;
      }
    }
  }

  float mx[4] = {0.f, 0.f, 0.f, 0.f};
#pragma unroll
  for (int jj = 0; jj < 9; ++jj)
    if (jj < jn) {
#pragma unroll
      for (int r = 0; r < 4; ++r) {
        float v = sc[jj][r] * 0.125f;
        sc[jj][r] = v;
        int tg = tw + quad * 4 + r;
        int sg = t0 - 256 + 16 * (rt + j0 + jj) + m;
        if (sg >= 0 && sg <= tg && tg - sg < 256) mx[r] = fmaxf(mx[r], v);
      }
    }
#pragma unroll
  for (int d = 1; d < 16; d <<= 1)
#pragma unroll
    for (int r = 0; r < 4; ++r) mx[r] = fmaxf(mx[r], __shfl_xor(mx[r], d, 64));
  if (m == 0)
#pragma unroll
    for (int r = 0; r < 4; ++r) pmaxs[half * 64 + rt * 16 + quad * 4 + r] = mx[r];

  __syncthreads();                       // B2: frag reads done + pmax visible

  float mxf[4], rden[4];
#pragma unroll
  for (int r = 0; r < 4; ++r) {
    int row = rt * 16 + quad * 4 + r;
    mxf[r] = fmaxf(pmaxs[row], pmaxs[64 + row]);
    rden[r] = 1.f / (dval[r] + 1e-30f);
  }
#pragma unroll
  for (int jj = 0; jj < 9; ++jj)
    if (jj < jn) {
#pragma unroll
      for (int r = 0; r < 4; ++r) {
        int tg = tw + quad * 4 + r;
        int sg = t0 - 256 + 16 * (rt + j0 + jj) + m;
        bool ib = (sg >= 0 && sg <= tg && tg - sg < 256);
        sc[jj][r] = ib ? __expf(sc[jj][r] - mxf[r]) * rden[r] : 0.f;
      }
    }

  // zero PADS: rows [rt*16,+16), 16 cols just outside this row-tile's window
  if (half == 0) {
    if (rt > 0) {
      int row = rt * 16 + (lane >> 2), col = 16 * rt - 16 + (lane & 3) * 4;
      ushort4 z; z.x = 0; z.y = 0; z.z = 0; z.w = 0;
      *(ushort4*)&Ps[row * 344 + col] = z;
    }
  } else {
    if (rt < 3) {
      int row = rt * 16 + (lane >> 2), col = 16 * rt + 272 + (lane & 3) * 4;
      ushort4 z; z.x = 0; z.y = 0; z.z = 0; z.w = 0;
      *(ushort4*)&Ps[row * 344 + col] = z;
    }
  }
  // scatter normalized P (rows rt*16+quad*4+r, cols 16*(rt+j)+m)
#pragma unroll
  for (int jj = 0; jj < 9; ++jj)
    if (jj < jn) {
      int col = 16 * (rt + j0 + jj) + m;
#pragma unroll
      for (int r = 0; r < 4; ++r)
        Ps[(rt * 16 + quad * 4 + r) * 344 + col] = f2bf(sc[jj][r]);
    }

  // V chunk-0 prefetch issued before the barrier (lands during drain)
  const int cbase = ch * 128 + w * 16;
  const unsigned short* vrow = vv + (size_t)(b * 256 + cbase + m) * TDIM;
  us8 vreg = {0, 0, 0, 0, 0, 0, 0, 0};
  if (t0 >= 256) vreg = *(const us8*)(vrow + t0 - 256 + quad * 8);

  __syncthreads();                       // B3: P visible

  // ---- PV: 10 V chunks; row-tile mt uses window [mt>>1, mt>>1 + 8] ----
  const f32x4 fz = {0.f, 0.f, 0.f, 0.f};
  f32x4 acc[4] = {fz, fz, fz, fz};
#pragma unroll
  for (int chunk = 0; chunk < 10; ++chunk) {
    us8 vnext = {0, 0, 0, 0, 0, 0, 0, 0};
    if (chunk < 9) {
      int sbase = t0 - 256 + (chunk + 1) * 32;
      if (sbase >= 0) vnext = *(const us8*)(vrow + sbase + quad * 8);
    }
    bf16x8 bfr = __builtin_bit_cast(bf16x8, vreg);
#pragma unroll
    for (int mt = 0; mt < 4; ++mt) {
      const int cs = mt >> 1;
      if (chunk >= cs && chunk <= cs + 8) {
        bf16x8 af = *(const bf16x8*)&Ps[(mt * 16 + m) * 344 + chunk * 32 + quad * 8];
        acc[mt] = __builtin_amdgcn_mfma_f32_16x16x32_bf16(af, bfr, acc[mt], 0, 0, 0);
      }
    }
    vreg = vnext;
  }

  // epilogue: out = x + O^T.  D: col (c) = m, row (t) = quad*4+r
#pragma unroll
  for (int mt = 0; mt < 4; ++mt) {
    int c = cbase + m;
    int t = t0 + mt * 16 + quad * 4;
    size_t off = (size_t)(b * 256 + c) * TDIM + t;
    float4 xv = *(const float4*)(x + off);
    float4 o;
    o.x = xv.x + acc[mt][0];
    o.y = xv.y + acc[mt][1];
    o.z = xv.z + acc[mt][2];
    o.w = xv.w + acc[mt][3];
    *(float4*)(out + off) = o;
  }
}

// ---------------------------------------------------------------------------
extern "C" void kernel_launch(void* const* d_in, const int* in_sizes, int n_in,
                              void* d_out, int out_size, void* d_ws, size_t ws_size,
                              hipStream_t stream) {
  const float* x   = (const float*)d_in[0];
  const float* kW  = (const float*)d_in[1];
  const float* kb  = (const float*)d_in[2];
  const float* kg  = (const float*)d_in[3];
  const float* kbe = (const float*)d_in[4];
  const float* kmu = (const float*)d_in[5];
  const float* kva = (const float*)d_in[6];
  const float* qW  = (const float*)d_in[7];
  const float* qb  = (const float*)d_in[8];
  const float* qg  = (const float*)d_in[9];
  const float* qbe = (const float*)d_in[10];
  const float* qmu = (const float*)d_in[11];
  const float* qva = (const float*)d_in[12];
  const float* vW  = (const float*)d_in[13];
  const float* vb  = (const float*)d_in[14];
  const float* vg  = (const float*)d_in[15];
  const float* vbe = (const float*)d_in[16];
  const float* vmu = (const float*)d_in[17];
  const float* vva = (const float*)d_in[18];

  unsigned short* vv  = (unsigned short*)d_ws;                  // 8 MB
  unsigned short* kTs = vv + (size_t)8 * 256 * TDIM;            // 2 MB
  unsigned short* qTs = kTs + (size_t)8 * TDIM * 64;            // 2 MB
  float* denom0 = (float*)(qTs + (size_t)8 * TDIM * 64);        // 8 KB
  unsigned short* effWf = (unsigned short*)(denom0 + 2048);     // 192 KB
  float* effb = (float*)(effWf + 12 * 8192);                    // 1.5 KB
  float* outp = (float*)d_out;

  k_prepw<<<dim3(12), 256, 0, stream>>>(
      kW, kb, kg, kbe, kmu, kva,
      qW, qb, qg, qbe, qmu, qva,
      vW, vb, vg, vbe, vmu, vva, effWf, effb);
  k_qkv<<<dim3(32, 3, 8), 256, 0, stream>>>(effWf, effb, x, vv, kTs, qTs);
  k_denom<<<dim3(128), 512, 0, stream>>>(kTs, qTs, denom0);
  k_attn<<<dim3(32, 2, 8), 512, 0, stream>>>(x, vv, kTs, qTs, denom0, outp);
}

// Round 5
// 133.617 us; speedup vs baseline: 1.3273x; 1.0003x over previous
//
#include <hip/hip_runtime.h>

#define TDIM 2048

typedef __bf16 bf16_t;
typedef bf16_t bf16x8 __attribute__((ext_vector_type(8)));
typedef float f32x4 __attribute__((ext_vector_type(4)));
typedef unsigned short us8 __attribute__((ext_vector_type(8)));

__device__ __forceinline__ unsigned short f2bf(float x) {
  unsigned u = __builtin_bit_cast(unsigned, x);
  u += 0x7fffu + ((u >> 16) & 1u);            // round-to-nearest-even
  return (unsigned short)(u >> 16);
}

// async global->LDS, 16B per lane; lds base wave-uniform (HW adds lane*16)
__device__ __forceinline__ void gl_lds16(const unsigned short* g, unsigned short* l) {
  __builtin_amdgcn_global_load_lds(
      (const __attribute__((address_space(1))) unsigned int*)g,
      (__attribute__((address_space(3))) unsigned int*)l, 16, 0, 0);
}

// ---------------------------------------------------------------------------
// K0: BN-fold weights -> effWf bf16 in MFMA-fragment order. grid 12 x 256.
// ---------------------------------------------------------------------------
__global__ __launch_bounds__(256) void k_prepw(
    const float* __restrict__ kW, const float* __restrict__ kb,
    const float* __restrict__ kg, const float* __restrict__ kbe,
    const float* __restrict__ kmu, const float* __restrict__ kva,
    const float* __restrict__ qW, const float* __restrict__ qb,
    const float* __restrict__ qg, const float* __restrict__ qbe,
    const float* __restrict__ qmu, const float* __restrict__ qva,
    const float* __restrict__ vW, const float* __restrict__ vb,
    const float* __restrict__ vg, const float* __restrict__ vbe,
    const float* __restrict__ vmu, const float* __restrict__ vva,
    unsigned short* __restrict__ effWf,
    float* __restrict__ effb)
{
  const int idx = blockIdx.x;            // gid*4 + cc
  const int tid = threadIdx.x;
  const int gid = idx >> 2, cc = idx & 3;
  unsigned short* dst = effWf + (size_t)idx * 8192;
#pragma unroll
  for (int pass = 0; pass < 4; ++pass) {
    int f = pass * 256 + tid;
    int ocblk = f >> 7, cblk = (f >> 4) & 7, m = f & 15;
    int G = gid * 128 + ocblk * 16 + m;
    const float* Wp = (G < 64) ? (kW + G * 256)
                     : (G < 128) ? (qW + (G - 64) * 256)
                                 : (vW + (G - 128) * 256);
    float gg = (G < 64) ? kg[G]  : (G < 128) ? qg[G - 64]  : vg[G - 128];
    float vr = (G < 64) ? kva[G] : (G < 128) ? qva[G - 64] : vva[G - 128];
    float inv = gg * rsqrtf(vr + 1e-5f);
    int c = cc * 64 + cblk * 8;
    float4 a = *(const float4*)(Wp + c);
    float4 bq = *(const float4*)(Wp + c + 4);
    ushort4 lo, hi;
    lo.x = f2bf(a.x * inv);  lo.y = f2bf(a.y * inv);
    lo.z = f2bf(a.z * inv);  lo.w = f2bf(a.w * inv);
    hi.x = f2bf(bq.x * inv); hi.y = f2bf(bq.y * inv);
    hi.z = f2bf(bq.z * inv); hi.w = f2bf(bq.w * inv);
    *(ushort4*)(dst + f * 8) = lo;
    *(ushort4*)(dst + f * 8 + 4) = hi;
  }
  if (idx == 0) {
    for (int G = tid; G < 384; G += 256) {
      float gg = (G < 64) ? kg[G]  : (G < 128) ? qg[G - 64]  : vg[G - 128];
      float vr = (G < 64) ? kva[G] : (G < 128) ? qva[G - 64] : vva[G - 128];
      float bb = (G < 64) ? kb[G]  : (G < 128) ? qb[G - 64]  : vb[G - 128];
      float mm = (G < 64) ? kmu[G] : (G < 128) ? qmu[G - 64] : vmu[G - 128];
      float be = (G < 64) ? kbe[G] : (G < 128) ? qbe[G - 64] : vbe[G - 128];
      float inv = gg * rsqrtf(vr + 1e-5f);
      effb[G] = (bb - mm) * inv + be;
    }
  }
}

// ---------------------------------------------------------------------------
// K1: QKV GEMM. W via global_load_lds (frag order), x transposed inline.
// grid (32 tb, 3 gid, 8 b), block 256 (4 waves), 3 wg/CU.
//   gid 0 -> K/Q transposed+pre-swizzled [b][t][64']; gid 1,2 -> V [b][c][t]
// ---------------------------------------------------------------------------
__global__ __launch_bounds__(256, 3) void k_qkv(
    const unsigned short* __restrict__ effWf,
    const float* __restrict__ effb,
    const float* __restrict__ x,
    unsigned short* __restrict__ vv,
    unsigned short* __restrict__ kTs,
    unsigned short* __restrict__ qTs)
{
  const int tb = blockIdx.x, gid = blockIdx.y, b = blockIdx.z;
  const int tid = threadIdx.x;
  const int lane = tid & 63, wv = tid >> 6;
  const int m = lane & 15, quad = lane >> 4;
  const int t0 = tb * 64;

  __shared__ unsigned short Wb[2][8192];   // 128oc x 64c chunk, frag order
  __shared__ unsigned short Xs[4608];      // 64t x 64c, XOR-swizzled (72 pitch)
  __shared__ float effbs[128];

  if (tid < 128) effbs[tid] = effb[gid * 128 + tid];

  const unsigned short* wbase = effWf + (size_t)gid * 32768;
  const float* xb = x + (size_t)b * 256 * TDIM + t0 + lane;

  float xr[16];

  auto stageW = [&](int cc, int bufi) {
    const unsigned short* ws = wbase + cc * 8192;
#pragma unroll
    for (int i = 0; i < 4; ++i) {
      int ii = wv * 4 + i;
      gl_lds16(ws + (ii * 64 + lane) * 8, &Wb[bufi][ii * 512]);
    }
  };
  auto loadX = [&](int cc) {
#pragma unroll
    for (int p = 0; p < 4; ++p)
#pragma unroll
      for (int j = 0; j < 4; ++j) {
        int c = cc * 64 + p * 16 + wv * 4 + j;
        xr[p * 4 + j] = xb[(size_t)c * TDIM];
      }
  };

  const f32x4 fz = {0.f, 0.f, 0.f, 0.f};
  f32x4 acc[2][4];
#pragma unroll
  for (int i = 0; i < 2; ++i)
#pragma unroll
    for (int j = 0; j < 4; ++j) acc[i][j] = fz;

  stageW(0, 0);
  loadX(0);
  for (int cc = 0; cc < 4; ++cc) {
    __syncthreads();                 // drains W(cc) glds; Xs WAR safe
#pragma unroll
    for (int p = 0; p < 4; ++p) {
      int cb4 = p * 16 + wv * 4;
      int swz = (((cb4 >> 3) ^ (lane >> 3)) << 3) | (cb4 & 7);
      ushort4 s4;
      s4.x = f2bf(xr[p * 4 + 0]); s4.y = f2bf(xr[p * 4 + 1]);
      s4.z = f2bf(xr[p * 4 + 2]); s4.w = f2bf(xr[p * 4 + 3]);
      *(ushort4*)&Xs[lane * 72 + swz] = s4;
    }
    if (cc < 3) { stageW(cc + 1, (cc + 1) & 1); loadX(cc + 1); }
    __syncthreads();                 // Xs visible
    const unsigned short* Wc = Wb[cc & 1];
#pragma unroll
    for (int kk = 0; kk < 2; ++kk) {
      int cb = kk * 4 + quad;
      bf16x8 af[2], bfv[4];
#pragma unroll
      for (int mt = 0; mt < 2; ++mt)
        af[mt] = *(const bf16x8*)&Wc[(((wv * 2 + mt) * 8 + cb) * 16 + m) * 8];
#pragma unroll
      for (int nt = 0; nt < 4; ++nt) {
        int t = nt * 16 + m;
        bfv[nt] = *(const bf16x8*)&Xs[t * 72 + ((cb ^ (t >> 3)) << 3)];
      }
#pragma unroll
      for (int mt = 0; mt < 2; ++mt)
#pragma unroll
        for (int nt = 0; nt < 4; ++nt)
          acc[mt][nt] = __builtin_amdgcn_mfma_f32_16x16x32_bf16(af[mt], bfv[nt], acc[mt][nt], 0, 0, 0);
    }
  }

  // epilogue. D layout: row (oc) = quad*4+r, col (t) = m
  if (gid == 0) {
#pragma unroll
    for (int mt = 0; mt < 2; ++mt)
#pragma unroll
      for (int nt = 0; nt < 4; ++nt) {
        int ocl = wv * 32 + mt * 16 + quad * 4;
        int t = t0 + nt * 16 + m;
        ushort4 s4;
        s4.x = f2bf(fmaxf(acc[mt][nt][0] + effbs[ocl + 0], 0.f));
        s4.y = f2bf(fmaxf(acc[mt][nt][1] + effbs[ocl + 1], 0.f));
        s4.z = f2bf(fmaxf(acc[mt][nt][2] + effbs[ocl + 2], 0.f));
        s4.w = f2bf(fmaxf(acc[mt][nt][3] + effbs[ocl + 3], 0.f));
        if (ocl < 64) {
          int col = (((ocl >> 3) ^ (t & 7)) << 3) | (ocl & 7);
          *(ushort4*)(kTs + ((size_t)(b * TDIM + t)) * 64 + col) = s4;
        } else {
          int oq = ocl - 64;
          int col = (((oq >> 3) ^ (t & 7)) << 3) | (oq & 7);
          *(ushort4*)(qTs + ((size_t)(b * TDIM + t)) * 64 + col) = s4;
        }
      }
  } else {
#pragma unroll
    for (int mt = 0; mt < 2; ++mt)
#pragma unroll
      for (int nt = 0; nt < 4; ++nt)
#pragma unroll
        for (int r = 0; r < 4; ++r) {
          int ocl = wv * 32 + mt * 16 + quad * 4 + r;
          float y = fmaxf(acc[mt][nt][r] + effbs[ocl], 0.f);
          int c = (gid - 1) * 128 + ocl;
          int t = t0 + nt * 16 + m;
          vv[(size_t)(b * 256 + c) * TDIM + t] = f2bf(y);
        }
  }
}

// ---------------------------------------------------------------------------
// K2: batch-0 row denominators (the reference's [0]-broadcast bug).
// grid 128 (16 rows each), block 512 (8 waves split the 17 s-tiles).
// ---------------------------------------------------------------------------
__global__ __launch_bounds__(512, 1) void k_denom(
    const unsigned short* __restrict__ kTs,
    const unsigned short* __restrict__ qTs,
    float* __restrict__ denom0)
{
  const int t0d = blockIdx.x * 16;
  const int tid = threadIdx.x;
  const int lane = tid & 63, w = tid >> 6;
  const int m = lane & 15, quad = lane >> 4;

  __shared__ unsigned short S[18432];     // Qs 16x64 | Ks 272x64
  unsigned short* Qs = S;
  unsigned short* Ks = S + 1024;
  __shared__ float pmaxs[8][16];
  __shared__ float psums[8][16];

  {
    const unsigned short* qg = qTs + (size_t)t0d * 64;
    const unsigned short* kg = kTs + ((long)t0d - 256) * 64;  // finite garbage, masked
#pragma unroll
    for (int it = 0; it < 5; ++it) {
      int j = it * 512 + tid;
      if (j < 2304) {
        const unsigned short* g = (j < 128) ? (qg + j * 8) : (kg + (size_t)(j - 128) * 8);
        gl_lds16(g, &S[(it * 512 + w * 64) * 8]);
      }
    }
  }
  __syncthreads();

  const int jn = (w == 0) ? 3 : 2;
  f32x4 sc[3];
  {
    int t = m;
    bf16x8 qf0 = *(const bf16x8*)&Qs[t * 64 + ((quad ^ (t & 7)) << 3)];
    bf16x8 qf1 = *(const bf16x8*)&Qs[t * 64 + (((4 + quad) ^ (t & 7)) << 3)];
    const f32x4 fz = {0.f, 0.f, 0.f, 0.f};
#pragma unroll
    for (int jj = 0; jj < 3; ++jj) {
      if (jj < jn) {
        int j = w + jj * 8;
        int sr = 16 * j + m;
        f32x4 a = fz;
        bf16x8 kf0 = *(const bf16x8*)&Ks[sr * 64 + ((quad ^ (sr & 7)) << 3)];
        a = __builtin_amdgcn_mfma_f32_16x16x32_bf16(qf0, kf0, a, 0, 0, 0);
        bf16x8 kf1 = *(const bf16x8*)&Ks[sr * 64 + (((4 + quad) ^ (sr & 7)) << 3)];
        a = __builtin_amdgcn_mfma_f32_16x16x32_bf16(qf1, kf1, a, 0, 0, 0);
        sc[jj] = a;
      }
    }
  }

  float mx[4] = {0.f, 0.f, 0.f, 0.f};
#pragma unroll
  for (int jj = 0; jj < 3; ++jj)
    if (jj < jn) {
      int j = w + jj * 8;
#pragma unroll
      for (int r = 0; r < 4; ++r) {
        float v = sc[jj][r] * 0.125f;
        sc[jj][r] = v;
        int tg = t0d + quad * 4 + r;
        int sg = t0d - 256 + 16 * j + m;
        if (sg >= 0 && sg <= tg && tg - sg < 256) mx[r] = fmaxf(mx[r], v);
      }
    }
#pragma unroll
  for (int d = 1; d < 16; d <<= 1)
#pragma unroll
    for (int r = 0; r < 4; ++r) mx[r] = fmaxf(mx[r], __shfl_xor(mx[r], d, 64));
  if (m == 0)
#pragma unroll
    for (int r = 0; r < 4; ++r) pmaxs[w][quad * 4 + r] = mx[r];
  __syncthreads();

  float mxf[4];
#pragma unroll
  for (int r = 0; r < 4; ++r) {
    float v = pmaxs[0][quad * 4 + r];
#pragma unroll
    for (int ww = 1; ww < 8; ++ww) v = fmaxf(v, pmaxs[ww][quad * 4 + r]);
    mxf[r] = v;
  }
  float sm[4] = {0.f, 0.f, 0.f, 0.f};
#pragma unroll
  for (int jj = 0; jj < 3; ++jj)
    if (jj < jn) {
      int j = w + jj * 8;
#pragma unroll
      for (int r = 0; r < 4; ++r) {
        int tg = t0d + quad * 4 + r;
        int sg = t0d - 256 + 16 * j + m;
        if (sg >= 0 && sg <= tg && tg - sg < 256) sm[r] += __expf(sc[jj][r] - mxf[r]);
      }
    }
#pragma unroll
  for (int d = 1; d < 16; d <<= 1)
#pragma unroll
    for (int r = 0; r < 4; ++r) sm[r] += __shfl_xor(sm[r], d, 64);
  if (m == 0)
#pragma unroll
    for (int r = 0; r < 4; ++r) psums[w][quad * 4 + r] = sm[r];
  __syncthreads();

  if (tid < 16) {
    float s = 0.f;
#pragma unroll
    for (int ww = 0; ww < 8; ++ww) s += psums[ww][tid];
    denom0[t0d + tid] = s;
  }
}

// ---------------------------------------------------------------------------
// K3: banded attention + residual, MERGED channels.
// grid (32 tb-swizzled, 8 b) = 256 wgs, block 512 (8 waves). Score computed
// ONCE per tile; PV gives each wave a 32-c strip (P A-frag reused for both
// c-tiles). XCD swizzle: consecutive tb share an XCD for V-band L2 reuse.
// ---------------------------------------------------------------------------
__global__ __launch_bounds__(512, 2) void k_attn(
    const float* __restrict__ x,
    const unsigned short* __restrict__ vv,
    const unsigned short* __restrict__ kTs,
    const unsigned short* __restrict__ qTs,
    const float* __restrict__ denom0,
    float* __restrict__ out)
{
  const int bx = blockIdx.x, b = blockIdx.y;
  const int tb = (bx >> 3) + 4 * (bx & 7);   // XCD-aware: same-XCD blocks get adjacent tb
  const int tid = threadIdx.x;
  const int lane = tid & 63, w = tid >> 6;
  const int m = lane & 15, quad = lane >> 4;
  const int t0 = tb * 64;

  // phase 1: Qs 64x64 (4096) + Ks 320x64 (20480); phase 2: Ps 64x344 (22016)
  __shared__ unsigned short SM[24576];
  __shared__ float pmaxs[128];          // [half][row]
  unsigned short* Qs = SM;
  unsigned short* Ks = SM + 4096;
  unsigned short* Ps = SM;

  {
    const unsigned short* qg = qTs + ((size_t)(b * TDIM + t0)) * 64;
    const unsigned short* kg = kTs + ((long)(b * TDIM + t0) - 256) * 64;  // finite garbage, masked
#pragma unroll
    for (int it = 0; it < 6; ++it) {
      int j = it * 512 + tid;
      const unsigned short* g = (j < 512) ? (qg + (size_t)j * 8)
                                          : (kg + (size_t)(j - 512) * 8);
      gl_lds16(g, &SM[(it * 512 + w * 64) * 8]);
    }
  }
  const int rt = w & 3, half = w >> 2;
  const int tw = t0 + rt * 16;
  float dval[4];
#pragma unroll
  for (int r = 0; r < 4; ++r) dval[r] = denom0[tw + quad * 4 + r];
  __syncthreads();                       // B1: staging drained

  const int j0 = half ? 9 : 0;
  const int jn = half ? 8 : 9;
  f32x4 sc[9];
  {
    int t = rt * 16 + m;
    bf16x8 qf0 = *(const bf16x8*)&Qs[t * 64 + ((quad ^ (t & 7)) << 3)];
    bf16x8 qf1 = *(const bf16x8*)&Qs[t * 64 + (((4 + quad) ^ (t & 7)) << 3)];
    const f32x4 fz = {0.f, 0.f, 0.f, 0.f};
#pragma unroll
    for (int jj = 0; jj < 9; ++jj) {
      if (jj < jn) {
        int sr = 16 * (rt + j0 + jj) + m;
        f32x4 a = fz;
        bf16x8 kf0 = *(const bf16x8*)&Ks[sr * 64 + ((quad ^ (sr & 7)) << 3)];
        a = __builtin_amdgcn_mfma_f32_16x16x32_bf16(qf0, kf0, a, 0, 0, 0);
        bf16x8 kf1 = *(const bf16x8*)&Ks[sr * 64 + (((4 + quad) ^ (sr & 7)) << 3)];
        a = __builtin_amdgcn_mfma_f32_16x16x32_bf16(qf1, kf1, a, 0, 0, 0);
        sc[jj] = a;
      }
    }
  }

  float mx[4] = {0.f, 0.f, 0.f, 0.f};
#pragma unroll
  for (int jj = 0; jj < 9; ++jj)
    if (jj < jn) {
#pragma unroll
      for (int r = 0; r < 4; ++r) {
        float v = sc[jj][r] * 0.125f;
        sc[jj][r] = v;
        int tg = tw + quad * 4 + r;
        int sg = t0 - 256 + 16 * (rt + j0 + jj) + m;
        if (sg >= 0 && sg <= tg && tg - sg < 256) mx[r] = fmaxf(mx[r], v);
      }
    }
#pragma unroll
  for (int d = 1; d < 16; d <<= 1)
#pragma unroll
    for (int r = 0; r < 4; ++r) mx[r] = fmaxf(mx[r], __shfl_xor(mx[r], d, 64));
  if (m == 0)
#pragma unroll
    for (int r = 0; r < 4; ++r) pmaxs[half * 64 + rt * 16 + quad * 4 + r] = mx[r];

  __syncthreads();                       // B2: frag reads done + pmax visible

  float mxf[4], rden[4];
#pragma unroll
  for (int r = 0; r < 4; ++r) {
    int row = rt * 16 + quad * 4 + r;
    mxf[r] = fmaxf(pmaxs[row], pmaxs[64 + row]);
    rden[r] = 1.f / (dval[r] + 1e-30f);
  }
#pragma unroll
  for (int jj = 0; jj < 9; ++jj)
    if (jj < jn) {
#pragma unroll
      for (int r = 0; r < 4; ++r) {
        int tg = tw + quad * 4 + r;
        int sg = t0 - 256 + 16 * (rt + j0 + jj) + m;
        bool ib = (sg >= 0 && sg <= tg && tg - sg < 256);
        sc[jj][r] = ib ? __expf(sc[jj][r] - mxf[r]) * rden[r] : 0.f;
      }
    }

  // zero PADS: rows [rt*16,+16), 16 cols just outside this row-tile's window
  if (half == 0) {
    if (rt > 0) {
      int row = rt * 16 + (lane >> 2), col = 16 * rt - 16 + (lane & 3) * 4;
      ushort4 z; z.x = 0; z.y = 0; z.z = 0; z.w = 0;
      *(ushort4*)&Ps[row * 344 + col] = z;
    }
  } else {
    if (rt < 3) {
      int row = rt * 16 + (lane >> 2), col = 16 * rt + 272 + (lane & 3) * 4;
      ushort4 z; z.x = 0; z.y = 0; z.z = 0; z.w = 0;
      *(ushort4*)&Ps[row * 344 + col] = z;
    }
  }
  // scatter normalized P (rows rt*16+quad*4+r, cols 16*(rt+j)+m)
#pragma unroll
  for (int jj = 0; jj < 9; ++jj)
    if (jj < jn) {
      int col = 16 * (rt + j0 + jj) + m;
#pragma unroll
      for (int r = 0; r < 4; ++r)
        Ps[(rt * 16 + quad * 4 + r) * 344 + col] = f2bf(sc[jj][r]);
    }

  // V chunk-0 prefetch (both c-tiles) issued before the barrier
  const int cbase = w * 32;
  const unsigned short* vrow0 = vv + (size_t)(b * 256 + cbase + m) * TDIM;
  const unsigned short* vrow1 = vrow0 + (size_t)16 * TDIM;
  us8 vreg0 = {0, 0, 0, 0, 0, 0, 0, 0}, vreg1 = {0, 0, 0, 0, 0, 0, 0, 0};
  if (t0 >= 256) {
    vreg0 = *(const us8*)(vrow0 + t0 - 256 + quad * 8);
    vreg1 = *(const us8*)(vrow1 + t0 - 256 + quad * 8);
  }

  __syncthreads();                       // B3: P visible

  // x-residual prefetch (overlaps PV)
  float4 xv[4][2];
#pragma unroll
  for (int mt = 0; mt < 4; ++mt)
#pragma unroll
    for (int ct = 0; ct < 2; ++ct) {
      int c = cbase + ct * 16 + m;
      int t = t0 + mt * 16 + quad * 4;
      xv[mt][ct] = *(const float4*)(x + (size_t)(b * 256 + c) * TDIM + t);
    }

  // ---- PV: 10 V chunks; row-tile mt uses window [mt>>1, mt>>1 + 8] ----
  const f32x4 fz = {0.f, 0.f, 0.f, 0.f};
  f32x4 acc[4][2];
#pragma unroll
  for (int i = 0; i < 4; ++i) { acc[i][0] = fz; acc[i][1] = fz; }
#pragma unroll
  for (int chunk = 0; chunk < 10; ++chunk) {
    us8 vn0 = {0, 0, 0, 0, 0, 0, 0, 0}, vn1 = {0, 0, 0, 0, 0, 0, 0, 0};
    if (chunk < 9) {
      int sbase = t0 - 256 + (chunk + 1) * 32;
      if (sbase >= 0) {
        vn0 = *(const us8*)(vrow0 + sbase + quad * 8);
        vn1 = *(const us8*)(vrow1 + sbase + quad * 8);
      }
    }
    bf16x8 bfr0 = __builtin_bit_cast(bf16x8, vreg0);
    bf16x8 bfr1 = __builtin_bit_cast(bf16x8, vreg1);
#pragma unroll
    for (int mt = 0; mt < 4; ++mt) {
      const int cs = mt >> 1;
      if (chunk >= cs && chunk <= cs + 8) {
        bf16x8 af = *(const bf16x8*)&Ps[(mt * 16 + m) * 344 + chunk * 32 + quad * 8];
        acc[mt][0] = __builtin_amdgcn_mfma_f32_16x16x32_bf16(af, bfr0, acc[mt][0], 0, 0, 0);
        acc[mt][1] = __builtin_amdgcn_mfma_f32_16x16x32_bf16(af, bfr1, acc[mt][1], 0, 0, 0);
      }
    }
    vreg0 = vn0; vreg1 = vn1;
  }

  // epilogue: out = x + O^T.  D: col (c) = m, row (t) = quad*4+r
#pragma unroll
  for (int mt = 0; mt < 4; ++mt)
#pragma unroll
    for (int ct = 0; ct < 2; ++ct) {
      int c = cbase + ct * 16 + m;
      int t = t0 + mt * 16 + quad * 4;
      size_t off = (size_t)(b * 256 + c) * TDIM + t;
      float4 o;
      o.x = xv[mt][ct].x + acc[mt][ct][0];
      o.y = xv[mt][ct].y + acc[mt][ct][1];
      o.z = xv[mt][ct].z + acc[mt][ct][2];
      o.w = xv[mt][ct].w + acc[mt][ct][3];
      *(float4*)(out + off) = o;
    }
}

// ---------------------------------------------------------------------------
extern "C" void kernel_launch(void* const* d_in, const int* in_sizes, int n_in,
                              void* d_out, int out_size, void* d_ws, size_t ws_size,
                              hipStream_t stream) {
  const float* x   = (const float*)d_in[0];
  const float* kW  = (const float*)d_in[1];
  const float* kb  = (const float*)d_in[2];
  const float* kg  = (const float*)d_in[3];
  const float* kbe = (const float*)d_in[4];
  const float* kmu = (const float*)d_in[5];
  const float* kva = (const float*)d_in[6];
  const float* qW  = (const float*)d_in[7];
  const float* qb  = (const float*)d_in[8];
  const float* qg  = (const float*)d_in[9];
  const float* qbe = (const float*)d_in[10];
  const float* qmu = (const float*)d_in[11];
  const float* qva = (const float*)d_in[12];
  const float* vW  = (const float*)d_in[13];
  const float* vb  = (const float*)d_in[14];
  const float* vg  = (const float*)d_in[15];
  const float* vbe = (const float*)d_in[16];
  const float* vmu = (const float*)d_in[17];
  const float* vva = (const float*)d_in[18];

  unsigned short* vv  = (unsigned short*)d_ws;                  // 8 MB
  unsigned short* kTs = vv + (size_t)8 * 256 * TDIM;            // 2 MB
  unsigned short* qTs = kTs + (size_t)8 * TDIM * 64;            // 2 MB
  float* denom0 = (float*)(qTs + (size_t)8 * TDIM * 64);        // 8 KB
  unsigned short* effWf = (unsigned short*)(denom0 + 2048);     // 192 KB
  float* effb = (float*)(effWf + 12 * 8192);                    // 1.5 KB
  float* outp = (float*)d_out;

  k_prepw<<<dim3(12), 256, 0, stream>>>(
      kW, kb, kg, kbe, kmu, kva,
      qW, qb, qg, qbe, qmu, qva,
      vW, vb, vg, vbe, vmu, vva, effWf, effb);
  k_qkv<<<dim3(32, 3, 8), 256, 0, stream>>>(effWf, effb, x, vv, kTs, qTs);
  k_denom<<<dim3(128), 512, 0, stream>>>(kTs, qTs, denom0);
  k_attn<<<dim3(32, 8), 512, 0, stream>>>(x, vv, kTs, qTs, denom0, outp);
}